// Round 16
// baseline (602.556 us; speedup 1.0000x reference)
//
#include <hip/hip_runtime.h>
#include <hip/hip_bf16.h>

#define BD 8
#define SD 1024
#define DM 1024
#define NH 16
#define DH 64
#define RK 128
#define NK 16384

typedef __attribute__((ext_vector_type(8))) short bf16x8;
typedef __attribute__((ext_vector_type(4))) float f32x4;

__device__ __forceinline__ unsigned short f2b(float f) {
    unsigned u = __float_as_uint(f);
    unsigned r = (u + 0x7FFFu + ((u >> 16) & 1u)) >> 16;
    return (unsigned short)r;
}
__device__ __forceinline__ float b2f(unsigned short h) {
    return __uint_as_float(((unsigned)h) << 16);
}

// ---------------- LayerNorm: bf16 hi/lo outputs ----------------
__global__ void __launch_bounds__(256) ln_kernel(const float* __restrict__ x,
                                                 const float* __restrict__ sc,
                                                 const float* __restrict__ bi,
                                                 unsigned short* __restrict__ outh,
                                                 unsigned short* __restrict__ outl) {
    const int tok = blockIdx.x;
    __shared__ float xs[DM];
    __shared__ float red[256];
    const float* xp = x + (size_t)tok * DM;
    float s = 0.f;
    for (int i = threadIdx.x; i < DM; i += 256) { float v = xp[i]; xs[i] = v; s += v; }
    red[threadIdx.x] = s; __syncthreads();
    for (int st = 128; st; st >>= 1) { if (threadIdx.x < st) red[threadIdx.x] += red[threadIdx.x + st]; __syncthreads(); }
    float mu = red[0] * (1.f / DM);
    __syncthreads();
    float vs = 0.f;
    for (int i = threadIdx.x; i < DM; i += 256) { float d = xs[i] - mu; vs += d * d; }
    red[threadIdx.x] = vs; __syncthreads();
    for (int st = 128; st; st >>= 1) { if (threadIdx.x < st) red[threadIdx.x] += red[threadIdx.x + st]; __syncthreads(); }
    float rs = rsqrtf(red[0] * (1.f / DM) + 1e-5f);
    for (int i = threadIdx.x; i < DM; i += 256) {
        float v = (xs[i] - mu) * rs * sc[i] + bi[i];
        unsigned short h = f2b(v);
        outh[(size_t)tok * DM + i] = h;
        outl[(size_t)tok * DM + i] = f2b(v - b2f(h));
    }
}

// ---------------- fused prep: concatw (blocks 0..1023) | tcvt WO (1024..1279) | cvt kK (1280..3327) ----------------
__global__ void __launch_bounds__(256) prep_kernel(const float* __restrict__ Wc,
                                                   const float* __restrict__ WQr,
                                                   const float* __restrict__ WKr,
                                                   const float* __restrict__ WVr,
                                                   const float* __restrict__ Wm,
                                                   unsigned short* __restrict__ WTh,
                                                   unsigned short* __restrict__ WTl,
                                                   const float* __restrict__ WO,
                                                   unsigned short* __restrict__ WOt,
                                                   const float* __restrict__ kK,
                                                   unsigned short* __restrict__ kKb) {
    __shared__ float ls[64][65];
    const int t = threadIdx.x;
    const int bid = blockIdx.x;
    if (bid < 1024) {
        const int i = bid * 256 + t;
        const int c = i >> 10, d = i & 1023;
        float v = 0.f;
        if (c < 64)       v = Wc[d * 64 + c];
        else if (c < 96)  v = WQr[d * 32 + c - 64];
        else if (c < 128) v = WKr[d * 32 + c - 96];
        else if (c < 160) v = WVr[d * 32 + c - 128];
        else if (c >= 192) v = Wm[d * 64 + c - 192];
        unsigned short h = f2b(v);
        WTh[i] = h;
        WTl[i] = f2b(v - b2f(h));
    } else if (bid < 1280) {
        const int bz = bid - 1024;
        const int r0 = (bz >> 4) * 64, c0 = (bz & 15) * 64;
        #pragma unroll
        for (int p = 0; p < 16; p++) {
            const int e = p * 256 + t;
            const int r = e >> 6, c = e & 63;
            ls[r][c] = WO[(size_t)(r0 + r) * DM + c0 + c];
        }
        __syncthreads();
        #pragma unroll
        for (int p = 0; p < 16; p++) {
            const int e = p * 256 + t;
            const int c = e >> 6, r = e & 63;
            WOt[(size_t)(c0 + c) * DM + r0 + r] = f2b(ls[r][c]);
        }
    } else {
        const int i = (bid - 1280) * 256 + t;
        const float scale = 0.0883883476483184f;
        float4 v = ((const float4*)kK)[i];
        unsigned r0 = (unsigned)f2b(v.x * scale) | ((unsigned)f2b(v.y * scale) << 16);
        unsigned r1 = (unsigned)f2b(v.z * scale) | ((unsigned)f2b(v.w * scale) << 16);
        uint2 o; o.x = r0; o.y = r1;
        ((uint2*)kKb)[i] = o;
    }
}

// ---------------- split-bf16 logits GEMM, BM=64 ----------------
__global__ void __launch_bounds__(256) gemm_split(const unsigned short* __restrict__ Ah,
                                                  const unsigned short* __restrict__ Al,
                                                  const unsigned short* __restrict__ Bh,
                                                  const unsigned short* __restrict__ Bl,
                                                  float* __restrict__ C,
                                                  int N, int K) {
    const int row0 = blockIdx.y * 64, col0 = blockIdx.x * 64;
    const int t = threadIdx.x;
    const int w = t >> 6, l = t & 63, lq = l & 15, lg = l >> 4;
    __shared__ unsigned short sAh[64 * 64];
    __shared__ unsigned short sAl[64 * 64];
    __shared__ unsigned short sBh[64 * 64];
    __shared__ unsigned short sBl[64 * 64];
    f32x4 acc[4];
    #pragma unroll
    for (int ni = 0; ni < 4; ni++) acc[ni] = f32x4{0.f, 0.f, 0.f, 0.f};

    for (int k0 = 0; k0 < K; k0 += 64) {
        __syncthreads();
        #pragma unroll
        for (int p = 0; p < 2; p++) {
            const int e = t * 8 + p * 2048;
            const int row = e >> 6, col = e & 63;
            const int sw = (e * 2) ^ ((row & 7) << 4);
            *(bf16x8*)((char*)sAh + sw) = *(const bf16x8*)(Ah + (size_t)(row0 + row) * K + k0 + col);
            *(bf16x8*)((char*)sAl + sw) = *(const bf16x8*)(Al + (size_t)(row0 + row) * K + k0 + col);
            *(bf16x8*)((char*)sBh + sw) = *(const bf16x8*)(Bh + (size_t)(col0 + row) * K + k0 + col);
            *(bf16x8*)((char*)sBl + sw) = *(const bf16x8*)(Bl + (size_t)(col0 + row) * K + k0 + col);
        }
        __syncthreads();
        #pragma unroll
        for (int kk = 0; kk < 2; kk++) {
            bf16x8 ah, al, bh[4], bl[4];
            {
                const int r = w * 16 + lq;
                const int off = (r * 128 + lg * 16 + kk * 64) ^ ((r & 7) << 4);
                ah = *(const bf16x8*)((const char*)sAh + off);
                al = *(const bf16x8*)((const char*)sAl + off);
            }
            #pragma unroll
            for (int ni = 0; ni < 4; ni++) {
                const int r = ni * 16 + lq;
                const int off = (r * 128 + lg * 16 + kk * 64) ^ ((r & 7) << 4);
                bh[ni] = *(const bf16x8*)((const char*)sBh + off);
                bl[ni] = *(const bf16x8*)((const char*)sBl + off);
            }
            #pragma unroll
            for (int ni = 0; ni < 4; ni++) {
                acc[ni] = __builtin_amdgcn_mfma_f32_16x16x32_bf16(ah, bh[ni], acc[ni], 0, 0, 0);
                acc[ni] = __builtin_amdgcn_mfma_f32_16x16x32_bf16(ah, bl[ni], acc[ni], 0, 0, 0);
                acc[ni] = __builtin_amdgcn_mfma_f32_16x16x32_bf16(al, bh[ni], acc[ni], 0, 0, 0);
            }
        }
    }
    #pragma unroll
    for (int j = 0; j < 4; j++) {
        const int row = row0 + w * 16 + lg * 4 + j;
        #pragma unroll
        for (int ni = 0; ni < 4; ni++)
            C[(size_t)row * N + col0 + ni * 16 + lq] = acc[ni][j];
    }
}

// ---------------- fused phase-1 softmax + chunk reduce ----------------
__global__ void __launch_bounds__(256) softpref_red(const float* __restrict__ lgt,
                                                    const float* __restrict__ imp,
                                                    float* __restrict__ partial) {
    const int b = blockIdx.x, chunk = blockIdx.y;
    __shared__ float wp[64][161];
    const int t = threadIdx.x;
    const int tl = t >> 2, sg = t & 3;
    const int tok = b * SD + chunk * 64 + tl;
    const int o = (sg == 0) ? 0 : (64 + 32 * (sg - 1));
    const int n = (sg == 0) ? 64 : 32;
    const float* lp = lgt + (size_t)tok * 192 + o;
    float m = -1e30f;
    for (int i = 0; i < n; i++) m = fmaxf(m, lp[i]);
    float ss = 0.f;
    for (int i = 0; i < n; i++) ss += __expf(lp[i] - m);
    const float scl = imp[tok] / ss;
    for (int i = 0; i < n; i++) wp[tl][o + i] = __expf(lp[i] - m) * scl;
    __syncthreads();
    if (t < 160) {
        float s = 0.f;
        for (int k = 0; k < 64; k++) s += wp[k][t];
        partial[((size_t)(b * 16 + chunk)) * 224 + t] = s;
    }
}

// ---------------- fused phase-2 softmax + chunk reduce ----------------
__global__ void __launch_bounds__(256) softm_red(const float* __restrict__ lgt,
                                                 const float* __restrict__ imp,
                                                 float* __restrict__ partial) {
    const int b = blockIdx.x, chunk = blockIdx.y;
    __shared__ float wp[64][65];
    const int t = threadIdx.x;
    if (t < 64) {
        const int tok = b * SD + chunk * 64 + t;
        const float* lp = lgt + (size_t)tok * 64;
        float m = -1e30f;
        for (int i = 0; i < 64; i++) m = fmaxf(m, lp[i]);
        float ss = 0.f;
        for (int i = 0; i < 64; i++) ss += __expf(lp[i] - m);
        const float scl = imp[tok] / ss;
        for (int i = 0; i < 64; i++) wp[t][i] = __expf(lp[i] - m) * scl;
    }
    __syncthreads();
    if (t < 64) {
        float s = 0.f;
        for (int k = 0; k < 64; k++) s += wp[k][t];
        partial[((size_t)(b * 16 + chunk)) * 224 + 160 + t] = s;
    }
}

// ---------------- top-k sparsify + renormalize (sums 16 chunk partials) ----------------
__global__ void topk_kernel(const float* __restrict__ partial,
                            int* __restrict__ ridx, float* __restrict__ rw,
                            int r0, int nr) {
    __shared__ float dv[40][65];
    const int t = threadIdx.x;
    if (t >= BD * nr) return;
    const int b = t / nr, r = r0 + (t % nr);
    const int offs[5] = {0, 64, 96, 128, 160};
    const int ns[5]   = {64, 32, 32, 32, 64};
    const int ks[5]   = {8, 4, 4, 4, 8};
    const int n = ns[r], k = ks[r], off = offs[r];
    for (int i = 0; i < n; i++) {
        float s = 0.f;
        for (int c = 0; c < 16; c++) s += partial[((size_t)(b * 16 + c)) * 224 + off + i];
        dv[t][i] = s;
    }
    unsigned long long mask = 0;
    float vals[8]; int idxs[8];
    float ssum = 0.f;
    for (int kk = 0; kk < k; kk++) {
        float best = -1e30f; int bi = 0;
        for (int i = 0; i < n; i++)
            if (!((mask >> i) & 1ull) && dv[t][i] > best) { best = dv[t][i]; bi = i; }
        mask |= 1ull << bi;
        vals[kk] = best; idxs[kk] = bi; ssum += best;
    }
    float inv = 1.f / (ssum + 1e-8f);
    for (int kk = 0; kk < 8; kk++) {
        ridx[(b * 5 + r) * 8 + kk] = (kk < k) ? idxs[kk] : 0;
        rw[(b * 5 + r) * 8 + kk]   = (kk < k) ? vals[kk] * inv : 0.f;
    }
}

// ---------------- fused mixtures: flat grid, blocks 0..255 scompT, 256..1023 E3t ----------------
__global__ void __launch_bounds__(256) combine_all_kernel(const float* __restrict__ cneu,
                                                          const float* __restrict__ epool,
                                                          const int* __restrict__ ridx,
                                                          const float* __restrict__ rw,
                                                          unsigned short* __restrict__ scompT,
                                                          unsigned short* __restrict__ E3t) {
    __shared__ float ls[64][65];
    const int t = threadIdx.x;
    const int bid = blockIdx.x;
    const float* pool;
    int b, router, r0, c0, Rp, Cp;
    unsigned short* op;
    if (bid < 256) {
        b = bid >> 5;
        const int rem = bid & 31;
        c0 = (rem & 1) * 64; r0 = (rem >> 1) * 64;
        Rp = DM; Cp = RK; router = 0; pool = cneu;
        op = scompT + (size_t)b * DM * RK;
    } else {
        const int e = bid - 256;
        const int z = e >> 5;
        const int rem = e & 31;
        c0 = (rem & 15) * 64; r0 = (rem >> 4) * 64;
        b = z & 7; router = 1 + (z >> 3);
        Rp = RK; Cp = DM; pool = epool;
        op = E3t + (size_t)b * 3 * DM * RK + (size_t)(router - 1) * DM * RK;
    }
    const int* ii = ridx + (b * 5 + router) * 8;
    const float* ww = rw + (b * 5 + router) * 8;
    const int kc = (router == 0) ? 8 : 4;
    const int rr = t >> 4, cc = (t & 15) * 4;
    #pragma unroll
    for (int p = 0; p < 4; p++) {
        const int r = rr + p * 16;
        float4 acc = {0.f, 0.f, 0.f, 0.f};
        for (int kk = 0; kk < kc; kk++) {
            const float w = ww[kk];
            float4 v = *(const float4*)&pool[((size_t)ii[kk] * Rp + r0 + r) * Cp + c0 + cc];
            acc.x += w * v.x; acc.y += w * v.y; acc.z += w * v.z; acc.w += w * v.w;
        }
        ls[r][cc] = acc.x; ls[r][cc + 1] = acc.y; ls[r][cc + 2] = acc.z; ls[r][cc + 3] = acc.w;
    }
    __syncthreads();
    #pragma unroll
    for (int q = 0; q < 2; q++) {
        const int c = (t >> 3) + q * 32;
        const int r8 = (t & 7) * 8;
        union { unsigned short s[8]; bf16x8 v; } u;
        #pragma unroll
        for (int j = 0; j < 8; j++) u.s[j] = f2b(ls[r8 + j][c]);
        *(bf16x8*)(op + (size_t)(c0 + c) * Rp + r0 + r8) = u.v;
    }
}

// ---------------- single combine (phase 2 scompT) ----------------
__global__ void __launch_bounds__(256) combine_t_kernel(const float* __restrict__ pool,
                                                        const int* __restrict__ ridx,
                                                        const float* __restrict__ rw,
                                                        int router, int kc,
                                                        unsigned short* __restrict__ outT,
                                                        int Rp, int Cp, long long sOut) {
    const int b = blockIdx.z;
    const int r0 = blockIdx.y * 64, c0 = blockIdx.x * 64;
    __shared__ float ls[64][65];
    const int* ii = ridx + (b * 5 + router) * 8;
    const float* ww = rw + (b * 5 + router) * 8;
    const int t = threadIdx.x;
    const int rr = t >> 4, cc = (t & 15) * 4;
    #pragma unroll
    for (int p = 0; p < 4; p++) {
        const int r = rr + p * 16;
        float4 acc = {0.f, 0.f, 0.f, 0.f};
        for (int kk = 0; kk < kc; kk++) {
            const float w = ww[kk];
            float4 v = *(const float4*)&pool[((size_t)ii[kk] * Rp + r0 + r) * Cp + c0 + cc];
            acc.x += w * v.x; acc.y += w * v.y; acc.z += w * v.z; acc.w += w * v.w;
        }
        ls[r][cc] = acc.x; ls[r][cc + 1] = acc.y; ls[r][cc + 2] = acc.z; ls[r][cc + 3] = acc.w;
    }
    __syncthreads();
    unsigned short* op = outT + (size_t)b * sOut;
    #pragma unroll
    for (int q = 0; q < 2; q++) {
        const int c = (t >> 3) + q * 32;
        const int r8 = (t & 7) * 8;
        union { unsigned short s[8]; bf16x8 v; } u;
        #pragma unroll
        for (int j = 0; j < 8; j++) u.s[j] = f2b(ls[r8 + j][c]);
        *(bf16x8*)(op + (size_t)(c0 + c) * Rp + r0 + r8) = u.v;
    }
}

// ---------------- bf16 MFMA GEMM: C = A[M][K] @ Bt[N][K]^T (+X), 128x128 tile ----------------
template<int OUTB, int HASX>
__global__ void __launch_bounds__(256) gemm_bf16(const unsigned short* __restrict__ A,
                                                 const unsigned short* __restrict__ Bt,
                                                 const float* __restrict__ X,
                                                 void* __restrict__ Cv,
                                                 int M, int N, int K,
                                                 long long sA, long long sB, long long sC) {
    const int bz = blockIdx.z;
    const unsigned short* Ab = A + (size_t)bz * sA;
    const unsigned short* Btb = Bt + (size_t)bz * sB;
    const int row0 = blockIdx.y * 128, col0 = blockIdx.x * 128;
    const int t = threadIdx.x;
    const int w = t >> 6, l = t & 63, lq = l & 15, lg = l >> 4;
    const int wr = w >> 1, wc = w & 1;
    __shared__ unsigned short As[128 * 64];
    __shared__ unsigned short Bs[128 * 64];
    f32x4 acc[4][4];
    #pragma unroll
    for (int mi = 0; mi < 4; mi++)
        #pragma unroll
        for (int ni = 0; ni < 4; ni++) acc[mi][ni] = f32x4{0.f, 0.f, 0.f, 0.f};

    for (int k0 = 0; k0 < K; k0 += 64) {
        __syncthreads();
        #pragma unroll
        for (int p = 0; p < 4; p++) {
            const int e = t * 8 + p * 2048;
            const int row = e >> 6, col = e & 63;
            bf16x8 va = *(const bf16x8*)(Ab + (size_t)(row0 + row) * K + k0 + col);
            *(bf16x8*)((char*)As + ((row * 128 + col * 2) ^ ((row & 7) << 4))) = va;
            bf16x8 vb = *(const bf16x8*)(Btb + (size_t)(col0 + row) * K + k0 + col);
            *(bf16x8*)((char*)Bs + ((row * 128 + col * 2) ^ ((row & 7) << 4))) = vb;
        }
        __syncthreads();
        #pragma unroll
        for (int kk = 0; kk < 2; kk++) {
            bf16x8 af[4], bg[4];
            #pragma unroll
            for (int mi = 0; mi < 4; mi++) {
                const int r = wr * 64 + mi * 16 + lq;
                af[mi] = *(const bf16x8*)((const char*)As + ((r * 128 + lg * 16 + kk * 64) ^ ((r & 7) << 4)));
            }
            #pragma unroll
            for (int ni = 0; ni < 4; ni++) {
                const int r = wc * 64 + ni * 16 + lq;
                bg[ni] = *(const bf16x8*)((const char*)Bs + ((r * 128 + lg * 16 + kk * 64) ^ ((r & 7) << 4)));
            }
            #pragma unroll
            for (int mi = 0; mi < 4; mi++)
                #pragma unroll
                for (int ni = 0; ni < 4; ni++)
                    acc[mi][ni] = __builtin_amdgcn_mfma_f32_16x16x32_bf16(af[mi], bg[ni], acc[mi][ni], 0, 0, 0);
        }
    }
    #pragma unroll
    for (int mi = 0; mi < 4; mi++) {
        #pragma unroll
        for (int j = 0; j < 4; j++) {
            const int row = row0 + wr * 64 + mi * 16 + lg * 4 + j;
            #pragma unroll
            for (int ni = 0; ni < 4; ni++) {
                const int col = col0 + wc * 64 + ni * 16 + lq;
                float v = acc[mi][ni][j];
                if (HASX) v += X[(size_t)row * N + col];
                if (OUTB) ((unsigned short*)Cv)[(size_t)bz * sC + (size_t)row * N + col] = f2b(v);
                else      ((float*)Cv)[(size_t)bz * sC + (size_t)row * N + col] = v;
            }
        }
    }
}

// ---------------- narrow GEMM for h/Qm: BM=64, N=128 fixed, bf16 out ----------------
__global__ void __launch_bounds__(256) gemm_h(const unsigned short* __restrict__ A,
                                              const unsigned short* __restrict__ Bt,
                                              unsigned short* __restrict__ C,
                                              int K,
                                              long long sA, long long sB, long long sC) {
    const int bz = blockIdx.z;
    const unsigned short* Ab = A + (size_t)bz * sA;
    const unsigned short* Btb = Bt + (size_t)bz * sB;
    const int row0 = blockIdx.y * 64;
    const int t = threadIdx.x;
    const int w = t >> 6, l = t & 63, lq = l & 15, lg = l >> 4;
    __shared__ unsigned short As[64 * 64];
    __shared__ unsigned short Bs[128 * 64];
    f32x4 acc[8];
    #pragma unroll
    for (int ni = 0; ni < 8; ni++) acc[ni] = f32x4{0.f, 0.f, 0.f, 0.f};

    for (int k0 = 0; k0 < K; k0 += 64) {
        __syncthreads();
        #pragma unroll
        for (int p = 0; p < 2; p++) {
            const int e = t * 8 + p * 2048;
            const int row = e >> 6, col = e & 63;
            bf16x8 va = *(const bf16x8*)(Ab + (size_t)(row0 + row) * K + k0 + col);
            *(bf16x8*)((char*)As + ((row * 128 + col * 2) ^ ((row & 7) << 4))) = va;
        }
        #pragma unroll
        for (int p = 0; p < 4; p++) {
            const int e = t * 8 + p * 2048;
            const int row = e >> 6, col = e & 63;
            bf16x8 vb = *(const bf16x8*)(Btb + (size_t)row * K + k0 + col);
            *(bf16x8*)((char*)Bs + ((row * 128 + col * 2) ^ ((row & 7) << 4))) = vb;
        }
        __syncthreads();
        #pragma unroll
        for (int kk = 0; kk < 2; kk++) {
            const int ra = w * 16 + lq;
            bf16x8 af = *(const bf16x8*)((const char*)As + ((ra * 128 + lg * 16 + kk * 64) ^ ((ra & 7) << 4)));
            #pragma unroll
            for (int ni = 0; ni < 8; ni++) {
                const int r = ni * 16 + lq;
                bf16x8 bg = *(const bf16x8*)((const char*)Bs + ((r * 128 + lg * 16 + kk * 64) ^ ((r & 7) << 4)));
                acc[ni] = __builtin_amdgcn_mfma_f32_16x16x32_bf16(af, bg, acc[ni], 0, 0, 0);
            }
        }
    }
    #pragma unroll
    for (int j = 0; j < 4; j++) {
        const int row = row0 + w * 16 + lg * 4 + j;
        #pragma unroll
        for (int ni = 0; ni < 8; ni++)
            C[(size_t)bz * sC + (size_t)row * 128 + ni * 16 + lq] = f2b(acc[ni][j]);
    }
}

// ---------------- flash attention: paired q-tiles, dbuf K/V, strided QKV input ----------------
#define SWZV(d) (((((d) >> 1) ^ ((d) >> 3)) & 7) << 4)
__global__ void __launch_bounds__(256) attn_mfma_kernel(const unsigned short* __restrict__ Q,
                                                        const unsigned short* __restrict__ K,
                                                        const unsigned short* __restrict__ V,
                                                        unsigned short* __restrict__ O,
                                                        int ldq) {
    const int qt = blockIdx.x, hh = blockIdx.y, b = blockIdx.z;
    const int t = threadIdx.x;
    const int w = t >> 6, l = t & 63, lq = l & 15, lg = l >> 4;

    __shared__ unsigned short ks[2][64 * 64];
    __shared__ unsigned short vt[2][64 * 64];
    __shared__ unsigned short pl[4][16 * 64];

    const size_t base = (size_t)b * SD * ldq + (size_t)hh * DH;
    const size_t obase = (size_t)b * SD * DM + (size_t)hh * DH;
    const int qA = qt;
    const int qB = 15 - qt;

    bf16x8 aqA[2], aqB[2];
    {
        const unsigned short* qp = Q + base + (size_t)(qA * 64 + w * 16 + lq) * ldq + lg * 8;
        aqA[0] = *(const bf16x8*)qp; aqA[1] = *(const bf16x8*)(qp + 32);
        const unsigned short* qp2 = Q + base + (size_t)(qB * 64 + w * 16 + lq) * ldq + lg * 8;
        aqB[0] = *(const bf16x8*)qp2; aqB[1] = *(const bf16x8*)(qp2 + 32);
    }

    f32x4 oA[4], oB[4];
    #pragma unroll
    for (int dt = 0; dt < 4; dt++) { oA[dt] = f32x4{0.f,0.f,0.f,0.f}; oB[dt] = f32x4{0.f,0.f,0.f,0.f}; }
    float mA[4] = {-1e30f,-1e30f,-1e30f,-1e30f}, sA[4] = {0.f,0.f,0.f,0.f};
    float mB[4] = {-1e30f,-1e30f,-1e30f,-1e30f}, sB[4] = {0.f,0.f,0.f,0.f};

    const int ntile = 16 - qt;
    const int srow = t >> 3;
    const int scol = (t & 7) * 8;

    int cur = 0;

    #pragma unroll
    for (int p = 0; p < 2; p++) {
        const int row = srow + 32 * p;
        bf16x8 kv = *(const bf16x8*)(K + base + (size_t)row * ldq + scol);
        *(bf16x8*)((char*)&ks[0][0] + ((row * 128 + scol * 2) ^ ((row & 7) << 4))) = kv;
        bf16x8 vv = *(const bf16x8*)(V + base + (size_t)row * ldq + scol);
        #pragma unroll
        for (int j2 = 0; j2 < 8; j2++) {
            const int d = scol + j2;
            *(unsigned short*)((char*)&vt[0][0] + ((d * 128 + row * 2) ^ SWZV(d))) = (unsigned short)vv[j2];
        }
    }
    __syncthreads();

    auto compute = [&](int q0, const bf16x8* aq, f32x4* o_, float* m_, float* s_, int kt) {
        const f32x4 zero4 = {0.f, 0.f, 0.f, 0.f};
        f32x4 sacc[4];
        __builtin_amdgcn_s_setprio(1);
        #pragma unroll
        for (int ct = 0; ct < 4; ct++) {
            const int krow = ct * 16 + lq;
            bf16x8 b0 = *(const bf16x8*)((const char*)&ks[cur][0] + ((krow * 128 + lg * 16) ^ ((lq & 7) << 4)));
            bf16x8 b1 = *(const bf16x8*)((const char*)&ks[cur][0] + ((krow * 128 + lg * 16 + 64) ^ ((lq & 7) << 4)));
            f32x4 s = __builtin_amdgcn_mfma_f32_16x16x32_bf16(aq[0], b0, zero4, 0, 0, 0);
            s = __builtin_amdgcn_mfma_f32_16x16x32_bf16(aq[1], b1, s, 0, 0, 0);
            sacc[ct] = s;
        }
        __builtin_amdgcn_s_setprio(0);
        float tm[4];
        #pragma unroll
        for (int j = 0; j < 4; j++) {
            const int qg = q0 * 64 + w * 16 + lg * 4 + j;
            float mx = -1e30f;
            #pragma unroll
            for (int ct = 0; ct < 4; ct++) {
                const int kg = kt * 64 + ct * 16 + lq;
                float v = sacc[ct][j] * 0.125f;
                v = (kg <= qg) ? v : -1e30f;
                sacc[ct][j] = v;
                mx = fmaxf(mx, v);
            }
            #pragma unroll
            for (int d = 1; d < 16; d <<= 1) mx = fmaxf(mx, __shfl_xor(mx, d));
            tm[j] = mx;
        }
        #pragma unroll
        for (int j = 0; j < 4; j++) {
            const float nm = fmaxf(m_[j], tm[j]);
            const float so = __expf(m_[j] - nm);
            m_[j] = nm;
            float rs = 0.f;
            const int prow = lg * 4 + j;
            #pragma unroll
            for (int ct = 0; ct < 4; ct++) {
                const float p = __expf(sacc[ct][j] - nm);
                rs += p;
                const int byteoff = ((prow * 128) + (ct * 16 + lq) * 2) ^ ((prow & 7) << 4);
                *(unsigned short*)((char*)&pl[w][0] + byteoff) = f2b(p);
            }
            #pragma unroll
            for (int d = 1; d < 16; d <<= 1) rs += __shfl_xor(rs, d);
            s_[j] = s_[j] * so + rs;
            #pragma unroll
            for (int dt = 0; dt < 4; dt++) o_[dt][j] *= so;
        }
        asm volatile("s_waitcnt lgkmcnt(0)" ::: "memory");
        __builtin_amdgcn_sched_barrier(0);
        __builtin_amdgcn_s_setprio(1);
        #pragma unroll
        for (int c = 0; c < 2; c++) {
            bf16x8 pa = *(const bf16x8*)((const char*)&pl[w][0] +
                          ((lq * 128 + lg * 16 + 64 * c) ^ ((lq & 7) << 4)));
            #pragma unroll
            for (int dt = 0; dt < 4; dt++) {
                const int dd = dt * 16 + lq;
                bf16x8 bv = *(const bf16x8*)((const char*)&vt[cur][0] +
                              ((dd * 128 + lg * 16 + 64 * c) ^ SWZV(dd)));
                o_[dt] = __builtin_amdgcn_mfma_f32_16x16x32_bf16(pa, bv, o_[dt], 0, 0, 0);
            }
        }
        __builtin_amdgcn_s_setprio(0);
    };

    const int mymaxA = qA * 64 + w * 16 + 15;
    for (int kt = 0; kt < ntile; kt++) {
        bf16x8 kN[2], vN[2];
        const bool pre = (kt + 1 < ntile);
        if (pre) {
            #pragma unroll
            for (int p = 0; p < 2; p++) {
                const int row = srow + 32 * p;
                kN[p] = *(const bf16x8*)(K + base + (size_t)((kt + 1) * 64 + row) * ldq + scol);
                vN[p] = *(const bf16x8*)(V + base + (size_t)((kt + 1) * 64 + row) * ldq + scol);
            }
        }
        compute(qB, aqB, oB, mB, sB, kt);
        if (kt * 64 <= mymaxA) compute(qA, aqA, oA, mA, sA, kt);
        if (pre) {
            #pragma unroll
            for (int p = 0; p < 2; p++) {
                const int row = srow + 32 * p;
                *(bf16x8*)((char*)&ks[cur ^ 1][0] + ((row * 128 + scol * 2) ^ ((row & 7) << 4))) = kN[p];
                #pragma unroll
                for (int j2 = 0; j2 < 8; j2++) {
                    const int d = scol + j2;
                    *(unsigned short*)((char*)&vt[cur ^ 1][0] + ((d * 128 + row * 2) ^ SWZV(d))) =
                        (unsigned short)vN[p][j2];
                }
            }
        }
        __syncthreads();
        cur ^= 1;
    }

    #pragma unroll
    for (int j = 0; j < 4; j++) {
        const float invA = 1.f / sA[j];
        const float invB = 1.f / sB[j];
        const int rowA = qA * 64 + w * 16 + lg * 4 + j;
        const int rowB = qB * 64 + w * 16 + lg * 4 + j;
        unsigned short* opA = O + obase + (size_t)rowA * DM;
        unsigned short* opB = O + obase + (size_t)rowB * DM;
        #pragma unroll
        for (int dt = 0; dt < 4; dt++) {
            opA[dt * 16 + lq] = f2b(oA[dt][j] * invA);
            opB[dt * 16 + lq] = f2b(oB[dt][j] * invB);
        }
    }
}
#undef SWZV

// ---------------- knowledge scores: LDS tiles + vote-skipped bitonic merge + wave top-8 ----------------
#define CE(a, b) { float hi_ = fmaxf(a, b), lo_ = fminf(a, b); a = hi_; b = lo_; }
__global__ void __launch_bounds__(512, 4) know_score_kernel(const unsigned short* __restrict__ Qmb,
                                                            const unsigned short* __restrict__ kKb,
                                                            float* __restrict__ cand) {
    const int t = threadIdx.x;
    const int w = t >> 6, l = t & 63, lq = l & 15, lg = l >> 4;
    const int tok0 = blockIdx.x * 16;
    __shared__ unsigned short ks[8][16 * 128];

    bf16x8 aq[4];
    {
        const unsigned short* qp = Qmb + (size_t)(tok0 + lq) * 128 + lg * 8;
        #pragma unroll
        for (int c = 0; c < 4; c++) aq[c] = *(const bf16x8*)(qp + c * 32);
    }

    float L[4][8];
    #pragma unroll
    for (int j = 0; j < 4; j++)
        #pragma unroll
        for (int s = 0; s < 8; s++) L[j][s] = __uint_as_float(0xF2000000u | (unsigned)s);

    const unsigned short* gsrc = kKb + (((size_t)w * 2048) << 7) + l * 8;
    unsigned short* myks = &ks[w][0];

    bf16x8 vreg[4];
    #pragma unroll
    for (int p = 0; p < 4; p++) vreg[p] = *(const bf16x8*)(gsrc + p * 512);

    for (int t4 = 0; t4 < 32; t4++) {
        float B[4][4];
        #pragma unroll
        for (int sub = 0; sub < 4; sub++) {
            const int kt = t4 * 4 + sub;
            #pragma unroll
            for (int p = 0; p < 4; p++) {
                const int e = p * 512 + l * 8;
                const int row = e >> 7;
                *(bf16x8*)((char*)myks + ((e * 2) ^ ((row & 7) << 4))) = vreg[p];
            }
            if (kt < 127) {
                const unsigned short* src2 = gsrc + (size_t)(kt + 1) * 2048;
                #pragma unroll
                for (int p = 0; p < 4; p++) vreg[p] = *(const bf16x8*)(src2 + p * 512);
            }
            {
                const char* kb = (const char*)myks + lq * 256;
                const int sw = (lq & 7) << 4;
                f32x4 s = {0.f, 0.f, 0.f, 0.f};
                #pragma unroll
                for (int c = 0; c < 4; c++) {
                    bf16x8 bv = *(const bf16x8*)(kb + ((c * 64 + lg * 16) ^ sw));
                    s = __builtin_amdgcn_mfma_f32_16x16x32_bf16(aq[c], bv, s, 0, 0, 0);
                }
                const unsigned keyb = (unsigned)(w * 2048 + kt * 16 + lq);
                #pragma unroll
                for (int j = 0; j < 4; j++) {
                    unsigned u = __float_as_uint(s[j]);
                    B[j][sub] = __uint_as_float((u & 0xFFFFC000u) | keyb);
                }
            }
        }
        #pragma unroll
        for (int j = 0; j < 4; j++) {
            const float bmax = fmaxf(fmaxf(B[j][0], B[j][1]), fmaxf(B[j][2], B[j][3]));
            if (__any(bmax > L[j][7])) {
                CE(B[j][0], B[j][2]); CE(B[j][1], B[j][3]);
                CE(B[j][0], B[j][1]); CE(B[j][2], B[j][3]);
                CE(B[j][1], B[j][2]);
                L[j][4] = fmaxf(L[j][4], B[j][3]);
                L[j][5] = fmaxf(L[j][5], B[j][2]);
                L[j][6] = fmaxf(L[j][6], B[j][1]);
                L[j][7] = fmaxf(L[j][7], B[j][0]);
                CE(L[j][0], L[j][4]); CE(L[j][1], L[j][5]); CE(L[j][2], L[j][6]); CE(L[j][3], L[j][7]);
                CE(L[j][0], L[j][2]); CE(L[j][1], L[j][3]); CE(L[j][4], L[j][6]); CE(L[j][5], L[j][7]);
                CE(L[j][0], L[j][1]); CE(L[j][2], L[j][3]); CE(L[j][4], L[j][5]); CE(L[j][6], L[j][7]);
            }
        }
    }
    // cross-lq butterfly merge: all 16 lq lanes -> wave top-8 per j
    #pragma unroll
    for (int j = 0; j < 4; j++) {
        #pragma unroll
        for (int d = 1; d < 16; d <<= 1) {
            float P[8];
            #pragma unroll
            for (int s = 0; s < 8; s++) P[s] = __shfl_xor(L[j][s], d);
            L[j][0] = fmaxf(L[j][0], P[7]);
            L[j][1] = fmaxf(L[j][1], P[6]);
            L[j][2] = fmaxf(L[j][2], P[5]);
            L[j][3] = fmaxf(L[j][3], P[4]);
            L[j][4] = fmaxf(L[j][4], P[3]);
            L[j][5] = fmaxf(L[j][5], P[2]);
            L[j][6] = fmaxf(L[j][6], P[1]);
            L[j][7] = fmaxf(L[j][7], P[0]);
            CE(L[j][0], L[j][4]); CE(L[j][1], L[j][5]); CE(L[j][2], L[j][6]); CE(L[j][3], L[j][7]);
            CE(L[j][0], L[j][2]); CE(L[j][1], L[j][3]); CE(L[j][4], L[j][6]); CE(L[j][5], L[j][7]);
            CE(L[j][0], L[j][1]); CE(L[j][2], L[j][3]); CE(L[j][4], L[j][5]); CE(L[j][6], L[j][7]);
        }
    }
    if (lq == 0) {
        #pragma unroll
        for (int j = 0; j < 4; j++) {
            const int tok = tok0 + lg * 4 + j;
            float* cp = cand + (size_t)tok * 64 + w * 8;
            #pragma unroll
            for (int ss = 0; ss < 8; ss++) cp[ss] = L[j][ss];
        }
    }
}
#undef CE

// ---------------- knowledge merge + V gather: one wave per token, 64 candidates ----------------
__global__ void __launch_bounds__(256) know_out_kernel(const float* __restrict__ cand,
                                                       const float* __restrict__ kV,
                                                       float* __restrict__ out) {
    const int t = threadIdx.x, w = t >> 6, l = t & 63;
    const int tok = blockIdx.x * 4 + w;
    float lv = cand[(size_t)tok * 64 + l];

    float topv[8]; int topi[8];
    #pragma unroll
    for (int kk = 0; kk < 8; kk++) {
        float m = lv;
        #pragma unroll
        for (int d = 1; d < 64; d <<= 1) m = fmaxf(m, __shfl_xor(m, d));
        topv[kk] = m;
        topi[kk] = (int)(__float_as_uint(m) & 0x3FFFu);
        lv = (lv == m) ? -1e31f : lv;
    }
    const float mx = topv[0];
    float e[8]; float ssum = 0.f;
    #pragma unroll
    for (int kk = 0; kk < 8; kk++) { e[kk] = __expf(topv[kk] - mx); ssum += e[kk]; }
    const float inv = 1.f / ssum;

    float4 acc[4];
    #pragma unroll
    for (int ch = 0; ch < 4; ch++) acc[ch] = float4{0.f, 0.f, 0.f, 0.f};
    #pragma unroll
    for (int kk = 0; kk < 8; kk++) {
        const float wk = e[kk] * inv;
        const float* vp = kV + ((size_t)topi[kk] << 10);
        #pragma unroll
        for (int ch = 0; ch < 4; ch++) {
            float4 v = *(const float4*)(vp + ch * 256 + l * 4);
            acc[ch].x += wk * v.x; acc[ch].y += wk * v.y;
            acc[ch].z += wk * v.z; acc[ch].w += wk * v.w;
        }
    }
    float* op = out + ((size_t)tok << 10);
    #pragma unroll
    for (int ch = 0; ch < 4; ch++) {
        float4 o = *(const float4*)(op + ch * 256 + l * 4);
        o.x += acc[ch].x; o.y += acc[ch].y; o.z += acc[ch].z; o.w += acc[ch].w;
        *(float4*)(op + ch * 256 + l * 4) = o;
    }
}

extern "C" void kernel_launch(void* const* d_in, const int* in_sizes, int n_in,
                              void* d_out, int out_size, void* d_ws, size_t ws_size,
                              hipStream_t stream) {
    const float* x    = (const float*)d_in[0];
    const float* imp  = (const float*)d_in[1];
    const float* Wc   = (const float*)d_in[2];
    const float* WQr  = (const float*)d_in[3];
    const float* WKr  = (const float*)d_in[4];
    const float* WVr  = (const float*)d_in[5];
    const float* Wm   = (const float*)d_in[6];
    const float* cneu = (const float*)d_in[7];
    const float* epool= (const float*)d_in[8];
    const float* kK   = (const float*)d_in[9];
    const float* kV   = (const float*)d_in[10];
    const float* WO   = (const float*)d_in[11];
    const float* ln1s = (const float*)d_in[12];
    const float* ln1b = (const float*)d_in[13];
    const float* ln2s = (const float*)d_in[14];
    const float* ln2b = (const float*)d_in[15];
    float* out = (float*)d_out;

    float* ws = (float*)d_ws;
    size_t o = 0;
    unsigned short* n1h = (unsigned short*)(ws + o); o += (size_t)BD * SD * DM / 2;
    unsigned short* n1l = (unsigned short*)(ws + o); o += (size_t)BD * SD * DM / 2;
    float* lgt   = ws + o; o += (size_t)BD * SD * 192;
    float* partial = ws + o; o += (size_t)BD * 16 * 224;
    int*   ridx  = (int*)(ws + o); o += (size_t)BD * 5 * 8;
    float* rw    = ws + o; o += (size_t)BD * 5 * 8;
    unsigned short* WTh = (unsigned short*)(ws + o); o += (size_t)256 * 1024 / 2;
    unsigned short* WTl = (unsigned short*)(ws + o); o += (size_t)256 * 1024 / 2;
    unsigned short* scompT = (unsigned short*)(ws + o); o += (size_t)BD * RK * DM / 2;
    unsigned short* E3t = (unsigned short*)(ws + o); o += (size_t)BD * 3 * DM * RK / 2;
    unsigned short* hb  = (unsigned short*)(ws + o); o += (size_t)BD * SD * RK / 2;
    unsigned short* QKV16 = (unsigned short*)(ws + o); o += (size_t)BD * SD * 3072 / 2;
    unsigned short* attnb = (unsigned short*)(ws + o); o += (size_t)BD * SD * DM / 2;
    unsigned short* WOt = (unsigned short*)(ws + o); o += (size_t)DM * DM / 2;
    unsigned short* kKb = (unsigned short*)(ws + o); o += (size_t)NK * RK / 2;
    unsigned short* Qmb = (unsigned short*)(ws + o); o += (size_t)BD * SD * RK / 2;
    float* cand = ws + o; o += (size_t)BD * SD * 64;

    const int NTOK = BD * SD;
    const long long sE3 = (long long)3 * DM * RK;

    // fused prep (concatw | tcvt WO | cvt kK)
    prep_kernel<<<3328, 256, 0, stream>>>(Wc, WQr, WKr, WVr, Wm, WTh, WTl, WO, WOt, kK, kKb);

    // phase 1
    ln_kernel<<<NTOK, 256, 0, stream>>>(x, ln1s, ln1b, n1h, n1l);
    gemm_split<<<dim3(3, NTOK / 64), 256, 0, stream>>>(n1h, n1l, WTh, WTl, lgt, 192, DM);
    softpref_red<<<dim3(BD, 16), 256, 0, stream>>>(lgt, imp, partial);
    topk_kernel<<<1, 64, 0, stream>>>(partial, ridx, rw, 0, 4);
    combine_all_kernel<<<1024, 256, 0, stream>>>(cneu, epool, ridx, rw, scompT, E3t);
    gemm_h<<<dim3(1, SD / 64, BD), 256, 0, stream>>>(n1h, scompT, hb,
        DM, (long long)SD * DM, (long long)RK * DM, (long long)SD * RK);
    gemm_bf16<1, 0><<<dim3(24, 8, BD), 256, 0, stream>>>(hb, E3t, nullptr, QKV16,
        SD, 3072, RK, (long long)SD * RK, sE3, (long long)SD * 3072);
    attn_mfma_kernel<<<dim3(8, NH, BD), 256, 0, stream>>>(QKV16, QKV16 + 1024, QKV16 + 2048,
        attnb, 3072);
    gemm_bf16<0, 1><<<dim3(8, 64, 1), 256, 0, stream>>>(attnb, WOt, x, out,
        NTOK, DM, DM, 0, 0, 0);

    // phase 2
    ln_kernel<<<NTOK, 256, 0, stream>>>(out, ln2s, ln2b, n1h, n1l);
    gemm_split<<<dim3(1, NTOK / 64), 256, 0, stream>>>(n1h, n1l,
        WTh + (size_t)192 * 1024, WTl + (size_t)192 * 1024, lgt, 64, DM);
    softm_red<<<dim3(BD, 16), 256, 0, stream>>>(lgt, imp, partial);
    topk_kernel<<<1, 64, 0, stream>>>(partial, ridx, rw, 4, 1);
    combine_t_kernel<<<dim3(2, 16, BD), 256, 0, stream>>>(cneu, ridx, rw, 4, 8, scompT, DM, RK,
        (long long)DM * RK);
    gemm_h<<<dim3(1, SD / 64, BD), 256, 0, stream>>>(n1h, scompT, Qmb,
        DM, (long long)SD * DM, (long long)RK * DM, (long long)SD * RK);
    know_score_kernel<<<NTOK / 16, 512, 0, stream>>>(Qmb, kKb, cand);
    know_out_kernel<<<NTOK / 4, 256, 0, stream>>>(cand, kV, out);
}

// Round 17
// 588.568 us; speedup vs baseline: 1.0238x; 1.0238x over previous
//
#include <hip/hip_runtime.h>
#include <hip/hip_bf16.h>

#define BD 8
#define SD 1024
#define DM 1024
#define NH 16
#define DH 64
#define RK 128
#define NK 16384

typedef __attribute__((ext_vector_type(8))) short bf16x8;
typedef __attribute__((ext_vector_type(4))) float f32x4;

__device__ __forceinline__ unsigned short f2b(float f) {
    unsigned u = __float_as_uint(f);
    unsigned r = (u + 0x7FFFu + ((u >> 16) & 1u)) >> 16;
    return (unsigned short)r;
}
__device__ __forceinline__ float b2f(unsigned short h) {
    return __uint_as_float(((unsigned)h) << 16);
}

// ---------------- LayerNorm: bf16 hi/lo outputs ----------------
__global__ void __launch_bounds__(256) ln_kernel(const float* __restrict__ x,
                                                 const float* __restrict__ sc,
                                                 const float* __restrict__ bi,
                                                 unsigned short* __restrict__ outh,
                                                 unsigned short* __restrict__ outl) {
    const int tok = blockIdx.x;
    __shared__ float xs[DM];
    __shared__ float red[256];
    const float* xp = x + (size_t)tok * DM;
    float s = 0.f;
    for (int i = threadIdx.x; i < DM; i += 256) { float v = xp[i]; xs[i] = v; s += v; }
    red[threadIdx.x] = s; __syncthreads();
    for (int st = 128; st; st >>= 1) { if (threadIdx.x < st) red[threadIdx.x] += red[threadIdx.x + st]; __syncthreads(); }
    float mu = red[0] * (1.f / DM);
    __syncthreads();
    float vs = 0.f;
    for (int i = threadIdx.x; i < DM; i += 256) { float d = xs[i] - mu; vs += d * d; }
    red[threadIdx.x] = vs; __syncthreads();
    for (int st = 128; st; st >>= 1) { if (threadIdx.x < st) red[threadIdx.x] += red[threadIdx.x + st]; __syncthreads(); }
    float rs = rsqrtf(red[0] * (1.f / DM) + 1e-5f);
    for (int i = threadIdx.x; i < DM; i += 256) {
        float v = (xs[i] - mu) * rs * sc[i] + bi[i];
        unsigned short h = f2b(v);
        outh[(size_t)tok * DM + i] = h;
        outl[(size_t)tok * DM + i] = f2b(v - b2f(h));
    }
}

// ---------------- fused prep: concatw (0..1023) | tcvt WO (1024..1279) | cvt kK (1280..3327) ----------------
__global__ void __launch_bounds__(256) prep_kernel(const float* __restrict__ Wc,
                                                   const float* __restrict__ WQr,
                                                   const float* __restrict__ WKr,
                                                   const float* __restrict__ WVr,
                                                   const float* __restrict__ Wm,
                                                   unsigned short* __restrict__ WTh,
                                                   unsigned short* __restrict__ WTl,
                                                   const float* __restrict__ WO,
                                                   unsigned short* __restrict__ WOt,
                                                   const float* __restrict__ kK,
                                                   unsigned short* __restrict__ kKb) {
    __shared__ float ls[64][65];
    const int t = threadIdx.x;
    const int bid = blockIdx.x;
    if (bid < 1024) {
        const int i = bid * 256 + t;
        const int c = i >> 10, d = i & 1023;
        float v = 0.f;
        if (c < 64)       v = Wc[d * 64 + c];
        else if (c < 96)  v = WQr[d * 32 + c - 64];
        else if (c < 128) v = WKr[d * 32 + c - 96];
        else if (c < 160) v = WVr[d * 32 + c - 128];
        else if (c >= 192) v = Wm[d * 64 + c - 192];
        unsigned short h = f2b(v);
        WTh[i] = h;
        WTl[i] = f2b(v - b2f(h));
    } else if (bid < 1280) {
        const int bz = bid - 1024;
        const int r0 = (bz >> 4) * 64, c0 = (bz & 15) * 64;
        #pragma unroll
        for (int p = 0; p < 16; p++) {
            const int e = p * 256 + t;
            const int r = e >> 6, c = e & 63;
            ls[r][c] = WO[(size_t)(r0 + r) * DM + c0 + c];
        }
        __syncthreads();
        #pragma unroll
        for (int p = 0; p < 16; p++) {
            const int e = p * 256 + t;
            const int c = e >> 6, r = e & 63;
            WOt[(size_t)(c0 + c) * DM + r0 + r] = f2b(ls[r][c]);
        }
    } else {
        const int i = (bid - 1280) * 256 + t;
        const float scale = 0.0883883476483184f;
        float4 v = ((const float4*)kK)[i];
        unsigned r0 = (unsigned)f2b(v.x * scale) | ((unsigned)f2b(v.y * scale) << 16);
        unsigned r1 = (unsigned)f2b(v.z * scale) | ((unsigned)f2b(v.w * scale) << 16);
        uint2 o; o.x = r0; o.y = r1;
        ((uint2*)kKb)[i] = o;
    }
}

// ---------------- split-bf16 logits GEMM, BM=64 (phase 1) ----------------
__global__ void __launch_bounds__(256) gemm_split(const unsigned short* __restrict__ Ah,
                                                  const unsigned short* __restrict__ Al,
                                                  const unsigned short* __restrict__ Bh,
                                                  const unsigned short* __restrict__ Bl,
                                                  float* __restrict__ C,
                                                  int N, int K) {
    const int row0 = blockIdx.y * 64, col0 = blockIdx.x * 64;
    const int t = threadIdx.x;
    const int w = t >> 6, l = t & 63, lq = l & 15, lg = l >> 4;
    __shared__ unsigned short sAh[64 * 64];
    __shared__ unsigned short sAl[64 * 64];
    __shared__ unsigned short sBh[64 * 64];
    __shared__ unsigned short sBl[64 * 64];
    f32x4 acc[4];
    #pragma unroll
    for (int ni = 0; ni < 4; ni++) acc[ni] = f32x4{0.f, 0.f, 0.f, 0.f};

    for (int k0 = 0; k0 < K; k0 += 64) {
        __syncthreads();
        #pragma unroll
        for (int p = 0; p < 2; p++) {
            const int e = t * 8 + p * 2048;
            const int row = e >> 6, col = e & 63;
            const int sw = (e * 2) ^ ((row & 7) << 4);
            *(bf16x8*)((char*)sAh + sw) = *(const bf16x8*)(Ah + (size_t)(row0 + row) * K + k0 + col);
            *(bf16x8*)((char*)sAl + sw) = *(const bf16x8*)(Al + (size_t)(row0 + row) * K + k0 + col);
            *(bf16x8*)((char*)sBh + sw) = *(const bf16x8*)(Bh + (size_t)(col0 + row) * K + k0 + col);
            *(bf16x8*)((char*)sBl + sw) = *(const bf16x8*)(Bl + (size_t)(col0 + row) * K + k0 + col);
        }
        __syncthreads();
        #pragma unroll
        for (int kk = 0; kk < 2; kk++) {
            bf16x8 ah, al, bh[4], bl[4];
            {
                const int r = w * 16 + lq;
                const int off = (r * 128 + lg * 16 + kk * 64) ^ ((r & 7) << 4);
                ah = *(const bf16x8*)((const char*)sAh + off);
                al = *(const bf16x8*)((const char*)sAl + off);
            }
            #pragma unroll
            for (int ni = 0; ni < 4; ni++) {
                const int r = ni * 16 + lq;
                const int off = (r * 128 + lg * 16 + kk * 64) ^ ((r & 7) << 4);
                bh[ni] = *(const bf16x8*)((const char*)sBh + off);
                bl[ni] = *(const bf16x8*)((const char*)sBl + off);
            }
            #pragma unroll
            for (int ni = 0; ni < 4; ni++) {
                acc[ni] = __builtin_amdgcn_mfma_f32_16x16x32_bf16(ah, bh[ni], acc[ni], 0, 0, 0);
                acc[ni] = __builtin_amdgcn_mfma_f32_16x16x32_bf16(ah, bl[ni], acc[ni], 0, 0, 0);
                acc[ni] = __builtin_amdgcn_mfma_f32_16x16x32_bf16(al, bh[ni], acc[ni], 0, 0, 0);
            }
        }
    }
    #pragma unroll
    for (int j = 0; j < 4; j++) {
        const int row = row0 + w * 16 + lg * 4 + j;
        #pragma unroll
        for (int ni = 0; ni < 4; ni++)
            C[(size_t)row * N + col0 + ni * 16 + lq] = acc[ni][j];
    }
}

// ---------------- fused phase-2 logits GEMM + softmax + chunk reduce (N=64) ----------------
__global__ void __launch_bounds__(256) gemm_split_sm2(const unsigned short* __restrict__ Ah,
                                                      const unsigned short* __restrict__ Al,
                                                      const unsigned short* __restrict__ Bh,
                                                      const unsigned short* __restrict__ Bl,
                                                      const float* __restrict__ imp,
                                                      float* __restrict__ partial) {
    const int row0 = blockIdx.x * 64;
    const int K = DM;
    const int t = threadIdx.x;
    const int w = t >> 6, l = t & 63, lq = l & 15, lg = l >> 4;
    __shared__ unsigned short sAh[64 * 64];
    __shared__ unsigned short sAl[64 * 64];
    __shared__ unsigned short sBh[64 * 64];
    __shared__ unsigned short sBl[64 * 64];
    __shared__ float wsm[64][65];
    f32x4 acc[4];
    #pragma unroll
    for (int ni = 0; ni < 4; ni++) acc[ni] = f32x4{0.f, 0.f, 0.f, 0.f};

    for (int k0 = 0; k0 < K; k0 += 64) {
        __syncthreads();
        #pragma unroll
        for (int p = 0; p < 2; p++) {
            const int e = t * 8 + p * 2048;
            const int row = e >> 6, col = e & 63;
            const int sw = (e * 2) ^ ((row & 7) << 4);
            *(bf16x8*)((char*)sAh + sw) = *(const bf16x8*)(Ah + (size_t)(row0 + row) * K + k0 + col);
            *(bf16x8*)((char*)sAl + sw) = *(const bf16x8*)(Al + (size_t)(row0 + row) * K + k0 + col);
            *(bf16x8*)((char*)sBh + sw) = *(const bf16x8*)(Bh + (size_t)(row) * K + k0 + col);
            *(bf16x8*)((char*)sBl + sw) = *(const bf16x8*)(Bl + (size_t)(row) * K + k0 + col);
        }
        __syncthreads();
        #pragma unroll
        for (int kk = 0; kk < 2; kk++) {
            bf16x8 ah, al, bh[4], bl[4];
            {
                const int r = w * 16 + lq;
                const int off = (r * 128 + lg * 16 + kk * 64) ^ ((r & 7) << 4);
                ah = *(const bf16x8*)((const char*)sAh + off);
                al = *(const bf16x8*)((const char*)sAl + off);
            }
            #pragma unroll
            for (int ni = 0; ni < 4; ni++) {
                const int r = ni * 16 + lq;
                const int off = (r * 128 + lg * 16 + kk * 64) ^ ((r & 7) << 4);
                bh[ni] = *(const bf16x8*)((const char*)sBh + off);
                bl[ni] = *(const bf16x8*)((const char*)sBl + off);
            }
            #pragma unroll
            for (int ni = 0; ni < 4; ni++) {
                acc[ni] = __builtin_amdgcn_mfma_f32_16x16x32_bf16(ah, bh[ni], acc[ni], 0, 0, 0);
                acc[ni] = __builtin_amdgcn_mfma_f32_16x16x32_bf16(ah, bl[ni], acc[ni], 0, 0, 0);
                acc[ni] = __builtin_amdgcn_mfma_f32_16x16x32_bf16(al, bh[ni], acc[ni], 0, 0, 0);
            }
        }
    }
    // per-row softmax over 64 cols (row = w*16+lg*4+j; cols spread over lq x ni)
    #pragma unroll
    for (int j = 0; j < 4; j++) {
        float mx = fmaxf(fmaxf(acc[0][j], acc[1][j]), fmaxf(acc[2][j], acc[3][j]));
        #pragma unroll
        for (int d = 1; d < 16; d <<= 1) mx = fmaxf(mx, __shfl_xor(mx, d));
        float e0 = __expf(acc[0][j] - mx), e1 = __expf(acc[1][j] - mx);
        float e2 = __expf(acc[2][j] - mx), e3 = __expf(acc[3][j] - mx);
        float ss = e0 + e1 + e2 + e3;
        #pragma unroll
        for (int d = 1; d < 16; d <<= 1) ss += __shfl_xor(ss, d);
        const int rl = w * 16 + lg * 4 + j;
        const float scl = imp[row0 + rl] / ss;
        wsm[rl][lq]      = e0 * scl;
        wsm[rl][16 + lq] = e1 * scl;
        wsm[rl][32 + lq] = e2 * scl;
        wsm[rl][48 + lq] = e3 * scl;
    }
    __syncthreads();
    if (t < 64) {
        float s = 0.f;
        for (int k = 0; k < 64; k++) s += wsm[k][t];
        const int b = row0 >> 10, chunk = (row0 >> 6) & 15;
        partial[((size_t)(b * 16 + chunk)) * 224 + 160 + t] = s;
    }
}

// ---------------- fused phase-1 softmax + chunk reduce ----------------
__global__ void __launch_bounds__(256) softpref_red(const float* __restrict__ lgt,
                                                    const float* __restrict__ imp,
                                                    float* __restrict__ partial) {
    const int b = blockIdx.x, chunk = blockIdx.y;
    __shared__ float wp[64][161];
    const int t = threadIdx.x;
    const int tl = t >> 2, sg = t & 3;
    const int tok = b * SD + chunk * 64 + tl;
    const int o = (sg == 0) ? 0 : (64 + 32 * (sg - 1));
    const int n = (sg == 0) ? 64 : 32;
    const float* lp = lgt + (size_t)tok * 192 + o;
    float m = -1e30f;
    for (int i = 0; i < n; i++) m = fmaxf(m, lp[i]);
    float ss = 0.f;
    for (int i = 0; i < n; i++) ss += __expf(lp[i] - m);
    const float scl = imp[tok] / ss;
    for (int i = 0; i < n; i++) wp[tl][o + i] = __expf(lp[i] - m) * scl;
    __syncthreads();
    if (t < 160) {
        float s = 0.f;
        for (int k = 0; k < 64; k++) s += wp[k][t];
        partial[((size_t)(b * 16 + chunk)) * 224 + t] = s;
    }
}

// ---------------- top-k sparsify + renormalize (sums 16 chunk partials) ----------------
__global__ void topk_kernel(const float* __restrict__ partial,
                            int* __restrict__ ridx, float* __restrict__ rw,
                            int r0, int nr) {
    __shared__ float dv[40][65];
    const int t = threadIdx.x;
    if (t >= BD * nr) return;
    const int b = t / nr, r = r0 + (t % nr);
    const int offs[5] = {0, 64, 96, 128, 160};
    const int ns[5]   = {64, 32, 32, 32, 64};
    const int ks[5]   = {8, 4, 4, 4, 8};
    const int n = ns[r], k = ks[r], off = offs[r];
    for (int i = 0; i < n; i++) {
        float s = 0.f;
        for (int c = 0; c < 16; c++) s += partial[((size_t)(b * 16 + c)) * 224 + off + i];
        dv[t][i] = s;
    }
    unsigned long long mask = 0;
    float vals[8]; int idxs[8];
    float ssum = 0.f;
    for (int kk = 0; kk < k; kk++) {
        float best = -1e30f; int bi = 0;
        for (int i = 0; i < n; i++)
            if (!((mask >> i) & 1ull) && dv[t][i] > best) { best = dv[t][i]; bi = i; }
        mask |= 1ull << bi;
        vals[kk] = best; idxs[kk] = bi; ssum += best;
    }
    float inv = 1.f / (ssum + 1e-8f);
    for (int kk = 0; kk < 8; kk++) {
        ridx[(b * 5 + r) * 8 + kk] = (kk < k) ? idxs[kk] : 0;
        rw[(b * 5 + r) * 8 + kk]   = (kk < k) ? vals[kk] * inv : 0.f;
    }
}

// ---------------- fused mixtures: flat grid, blocks 0..255 scompT, 256..1023 E3t ----------------
__global__ void __launch_bounds__(256) combine_all_kernel(const float* __restrict__ cneu,
                                                          const float* __restrict__ epool,
                                                          const int* __restrict__ ridx,
                                                          const float* __restrict__ rw,
                                                          unsigned short* __restrict__ scompT,
                                                          unsigned short* __restrict__ E3t) {
    __shared__ float ls[64][65];
    const int t = threadIdx.x;
    const int bid = blockIdx.x;
    const float* pool;
    int b, router, r0, c0, Rp, Cp;
    unsigned short* op;
    if (bid < 256) {
        b = bid >> 5;
        const int rem = bid & 31;
        c0 = (rem & 1) * 64; r0 = (rem >> 1) * 64;
        Rp = DM; Cp = RK; router = 0; pool = cneu;
        op = scompT + (size_t)b * DM * RK;
    } else {
        const int e = bid - 256;
        const int z = e >> 5;
        const int rem = e & 31;
        c0 = (rem & 15) * 64; r0 = (rem >> 4) * 64;
        b = z & 7; router = 1 + (z >> 3);
        Rp = RK; Cp = DM; pool = epool;
        op = E3t + (size_t)b * 3 * DM * RK + (size_t)(router - 1) * DM * RK;
    }
    const int* ii = ridx + (b * 5 + router) * 8;
    const float* ww = rw + (b * 5 + router) * 8;
    const int kc = (router == 0) ? 8 : 4;
    const int rr = t >> 4, cc = (t & 15) * 4;
    #pragma unroll
    for (int p = 0; p < 4; p++) {
        const int r = rr + p * 16;
        float4 acc = {0.f, 0.f, 0.f, 0.f};
        for (int kk = 0; kk < kc; kk++) {
            const float w = ww[kk];
            float4 v = *(const float4*)&pool[((size_t)ii[kk] * Rp + r0 + r) * Cp + c0 + cc];
            acc.x += w * v.x; acc.y += w * v.y; acc.z += w * v.z; acc.w += w * v.w;
        }
        ls[r][cc] = acc.x; ls[r][cc + 1] = acc.y; ls[r][cc + 2] = acc.z; ls[r][cc + 3] = acc.w;
    }
    __syncthreads();
    #pragma unroll
    for (int q = 0; q < 2; q++) {
        const int c = (t >> 3) + q * 32;
        const int r8 = (t & 7) * 8;
        union { unsigned short s[8]; bf16x8 v; } u;
        #pragma unroll
        for (int j = 0; j < 8; j++) u.s[j] = f2b(ls[r8 + j][c]);
        *(bf16x8*)(op + (size_t)(c0 + c) * Rp + r0 + r8) = u.v;
    }
}

// ---------------- single combine (phase 2 scompT) ----------------
__global__ void __launch_bounds__(256) combine_t_kernel(const float* __restrict__ pool,
                                                        const int* __restrict__ ridx,
                                                        const float* __restrict__ rw,
                                                        int router, int kc,
                                                        unsigned short* __restrict__ outT,
                                                        int Rp, int Cp, long long sOut) {
    const int b = blockIdx.z;
    const int r0 = blockIdx.y * 64, c0 = blockIdx.x * 64;
    __shared__ float ls[64][65];
    const int* ii = ridx + (b * 5 + router) * 8;
    const float* ww = rw + (b * 5 + router) * 8;
    const int t = threadIdx.x;
    const int rr = t >> 4, cc = (t & 15) * 4;
    #pragma unroll
    for (int p = 0; p < 4; p++) {
        const int r = rr + p * 16;
        float4 acc = {0.f, 0.f, 0.f, 0.f};
        for (int kk = 0; kk < kc; kk++) {
            const float w = ww[kk];
            float4 v = *(const float4*)&pool[((size_t)ii[kk] * Rp + r0 + r) * Cp + c0 + cc];
            acc.x += w * v.x; acc.y += w * v.y; acc.z += w * v.z; acc.w += w * v.w;
        }
        ls[r][cc] = acc.x; ls[r][cc + 1] = acc.y; ls[r][cc + 2] = acc.z; ls[r][cc + 3] = acc.w;
    }
    __syncthreads();
    unsigned short* op = outT + (size_t)b * sOut;
    #pragma unroll
    for (int q = 0; q < 2; q++) {
        const int c = (t >> 3) + q * 32;
        const int r8 = (t & 7) * 8;
        union { unsigned short s[8]; bf16x8 v; } u;
        #pragma unroll
        for (int j = 0; j < 8; j++) u.s[j] = f2b(ls[r8 + j][c]);
        *(bf16x8*)(op + (size_t)(c0 + c) * Rp + r0 + r8) = u.v;
    }
}

// ---------------- bf16 MFMA GEMM: C = A[M][K] @ Bt[N][K]^T (+X), 128x128 tile ----------------
template<int OUTB, int HASX>
__global__ void __launch_bounds__(256) gemm_bf16(const unsigned short* __restrict__ A,
                                                 const unsigned short* __restrict__ Bt,
                                                 const float* __restrict__ X,
                                                 void* __restrict__ Cv,
                                                 int M, int N, int K,
                                                 long long sA, long long sB, long long sC) {
    const int bz = blockIdx.z;
    const unsigned short* Ab = A + (size_t)bz * sA;
    const unsigned short* Btb = Bt + (size_t)bz * sB;
    const int row0 = blockIdx.y * 128, col0 = blockIdx.x * 128;
    const int t = threadIdx.x;
    const int w = t >> 6, l = t & 63, lq = l & 15, lg = l >> 4;
    const int wr = w >> 1, wc = w & 1;
    __shared__ unsigned short As[128 * 64];
    __shared__ unsigned short Bs[128 * 64];
    f32x4 acc[4][4];
    #pragma unroll
    for (int mi = 0; mi < 4; mi++)
        #pragma unroll
        for (int ni = 0; ni < 4; ni++) acc[mi][ni] = f32x4{0.f, 0.f, 0.f, 0.f};

    for (int k0 = 0; k0 < K; k0 += 64) {
        __syncthreads();
        #pragma unroll
        for (int p = 0; p < 4; p++) {
            const int e = t * 8 + p * 2048;
            const int row = e >> 6, col = e & 63;
            bf16x8 va = *(const bf16x8*)(Ab + (size_t)(row0 + row) * K + k0 + col);
            *(bf16x8*)((char*)As + ((row * 128 + col * 2) ^ ((row & 7) << 4))) = va;
            bf16x8 vb = *(const bf16x8*)(Btb + (size_t)(col0 + row) * K + k0 + col);
            *(bf16x8*)((char*)Bs + ((row * 128 + col * 2) ^ ((row & 7) << 4))) = vb;
        }
        __syncthreads();
        #pragma unroll
        for (int kk = 0; kk < 2; kk++) {
            bf16x8 af[4], bg[4];
            #pragma unroll
            for (int mi = 0; mi < 4; mi++) {
                const int r = wr * 64 + mi * 16 + lq;
                af[mi] = *(const bf16x8*)((const char*)As + ((r * 128 + lg * 16 + kk * 64) ^ ((r & 7) << 4)));
            }
            #pragma unroll
            for (int ni = 0; ni < 4; ni++) {
                const int r = wc * 64 + ni * 16 + lq;
                bg[ni] = *(const bf16x8*)((const char*)Bs + ((r * 128 + lg * 16 + kk * 64) ^ ((r & 7) << 4)));
            }
            #pragma unroll
            for (int mi = 0; mi < 4; mi++)
                #pragma unroll
                for (int ni = 0; ni < 4; ni++)
                    acc[mi][ni] = __builtin_amdgcn_mfma_f32_16x16x32_bf16(af[mi], bg[ni], acc[mi][ni], 0, 0, 0);
        }
    }
    #pragma unroll
    for (int mi = 0; mi < 4; mi++) {
        #pragma unroll
        for (int j = 0; j < 4; j++) {
            const int row = row0 + wr * 64 + mi * 16 + lg * 4 + j;
            #pragma unroll
            for (int ni = 0; ni < 4; ni++) {
                const int col = col0 + wc * 64 + ni * 16 + lq;
                float v = acc[mi][ni][j];
                if (HASX) v += X[(size_t)row * N + col];
                if (OUTB) ((unsigned short*)Cv)[(size_t)bz * sC + (size_t)row * N + col] = f2b(v);
                else      ((float*)Cv)[(size_t)bz * sC + (size_t)row * N + col] = v;
            }
        }
    }
}

// ---------------- narrow GEMM for h/Qm: BM=64, N=128 fixed, bf16 out ----------------
__global__ void __launch_bounds__(256) gemm_h(const unsigned short* __restrict__ A,
                                              const unsigned short* __restrict__ Bt,
                                              unsigned short* __restrict__ C,
                                              int K,
                                              long long sA, long long sB, long long sC) {
    const int bz = blockIdx.z;
    const unsigned short* Ab = A + (size_t)bz * sA;
    const unsigned short* Btb = Bt + (size_t)bz * sB;
    const int row0 = blockIdx.y * 64;
    const int t = threadIdx.x;
    const int w = t >> 6, l = t & 63, lq = l & 15, lg = l >> 4;
    __shared__ unsigned short As[64 * 64];
    __shared__ unsigned short Bs[128 * 64];
    f32x4 acc[8];
    #pragma unroll
    for (int ni = 0; ni < 8; ni++) acc[ni] = f32x4{0.f, 0.f, 0.f, 0.f};

    for (int k0 = 0; k0 < K; k0 += 64) {
        __syncthreads();
        #pragma unroll
        for (int p = 0; p < 2; p++) {
            const int e = t * 8 + p * 2048;
            const int row = e >> 6, col = e & 63;
            bf16x8 va = *(const bf16x8*)(Ab + (size_t)(row0 + row) * K + k0 + col);
            *(bf16x8*)((char*)As + ((row * 128 + col * 2) ^ ((row & 7) << 4))) = va;
        }
        #pragma unroll
        for (int p = 0; p < 4; p++) {
            const int e = t * 8 + p * 2048;
            const int row = e >> 6, col = e & 63;
            bf16x8 vb = *(const bf16x8*)(Btb + (size_t)row * K + k0 + col);
            *(bf16x8*)((char*)Bs + ((row * 128 + col * 2) ^ ((row & 7) << 4))) = vb;
        }
        __syncthreads();
        #pragma unroll
        for (int kk = 0; kk < 2; kk++) {
            const int ra = w * 16 + lq;
            bf16x8 af = *(const bf16x8*)((const char*)As + ((ra * 128 + lg * 16 + kk * 64) ^ ((ra & 7) << 4)));
            #pragma unroll
            for (int ni = 0; ni < 8; ni++) {
                const int r = ni * 16 + lq;
                bf16x8 bg = *(const bf16x8*)((const char*)Bs + ((r * 128 + lg * 16 + kk * 64) ^ ((r & 7) << 4)));
                acc[ni] = __builtin_amdgcn_mfma_f32_16x16x32_bf16(af, bg, acc[ni], 0, 0, 0);
            }
        }
    }
    #pragma unroll
    for (int j = 0; j < 4; j++) {
        const int row = row0 + w * 16 + lg * 4 + j;
        #pragma unroll
        for (int ni = 0; ni < 8; ni++)
            C[(size_t)bz * sC + (size_t)row * 128 + ni * 16 + lq] = f2b(acc[ni][j]);
    }
}

// ---------------- flash attention: paired q-tiles, dbuf K/V, strided QKV input ----------------
#define SWZV(d) (((((d) >> 1) ^ ((d) >> 3)) & 7) << 4)
__global__ void __launch_bounds__(256) attn_mfma_kernel(const unsigned short* __restrict__ Q,
                                                        const unsigned short* __restrict__ K,
                                                        const unsigned short* __restrict__ V,
                                                        unsigned short* __restrict__ O,
                                                        int ldq) {
    const int qt = blockIdx.x, hh = blockIdx.y, b = blockIdx.z;
    const int t = threadIdx.x;
    const int w = t >> 6, l = t & 63, lq = l & 15, lg = l >> 4;

    __shared__ unsigned short ks[2][64 * 64];
    __shared__ unsigned short vt[2][64 * 64];
    __shared__ unsigned short pl[4][16 * 64];

    const size_t base = (size_t)b * SD * ldq + (size_t)hh * DH;
    const size_t obase = (size_t)b * SD * DM + (size_t)hh * DH;
    const int qA = qt;
    const int qB = 15 - qt;

    bf16x8 aqA[2], aqB[2];
    {
        const unsigned short* qp = Q + base + (size_t)(qA * 64 + w * 16 + lq) * ldq + lg * 8;
        aqA[0] = *(const bf16x8*)qp; aqA[1] = *(const bf16x8*)(qp + 32);
        const unsigned short* qp2 = Q + base + (size_t)(qB * 64 + w * 16 + lq) * ldq + lg * 8;
        aqB[0] = *(const bf16x8*)qp2; aqB[1] = *(const bf16x8*)(qp2 + 32);
    }

    f32x4 oA[4], oB[4];
    #pragma unroll
    for (int dt = 0; dt < 4; dt++) { oA[dt] = f32x4{0.f,0.f,0.f,0.f}; oB[dt] = f32x4{0.f,0.f,0.f,0.f}; }
    float mA[4] = {-1e30f,-1e30f,-1e30f,-1e30f}, sA[4] = {0.f,0.f,0.f,0.f};
    float mB[4] = {-1e30f,-1e30f,-1e30f,-1e30f}, sB[4] = {0.f,0.f,0.f,0.f};

    const int ntile = 16 - qt;
    const int srow = t >> 3;
    const int scol = (t & 7) * 8;

    int cur = 0;

    #pragma unroll
    for (int p = 0; p < 2; p++) {
        const int row = srow + 32 * p;
        bf16x8 kv = *(const bf16x8*)(K + base + (size_t)row * ldq + scol);
        *(bf16x8*)((char*)&ks[0][0] + ((row * 128 + scol * 2) ^ ((row & 7) << 4))) = kv;
        bf16x8 vv = *(const bf16x8*)(V + base + (size_t)row * ldq + scol);
        #pragma unroll
        for (int j2 = 0; j2 < 8; j2++) {
            const int d = scol + j2;
            *(unsigned short*)((char*)&vt[0][0] + ((d * 128 + row * 2) ^ SWZV(d))) = (unsigned short)vv[j2];
        }
    }
    __syncthreads();

    auto compute = [&](int q0, const bf16x8* aq, f32x4* o_, float* m_, float* s_, int kt) {
        const f32x4 zero4 = {0.f, 0.f, 0.f, 0.f};
        f32x4 sacc[4];
        __builtin_amdgcn_s_setprio(1);
        #pragma unroll
        for (int ct = 0; ct < 4; ct++) {
            const int krow = ct * 16 + lq;
            bf16x8 b0 = *(const bf16x8*)((const char*)&ks[cur][0] + ((krow * 128 + lg * 16) ^ ((lq & 7) << 4)));
            bf16x8 b1 = *(const bf16x8*)((const char*)&ks[cur][0] + ((krow * 128 + lg * 16 + 64) ^ ((lq & 7) << 4)));
            f32x4 s = __builtin_amdgcn_mfma_f32_16x16x32_bf16(aq[0], b0, zero4, 0, 0, 0);
            s = __builtin_amdgcn_mfma_f32_16x16x32_bf16(aq[1], b1, s, 0, 0, 0);
            sacc[ct] = s;
        }
        __builtin_amdgcn_s_setprio(0);
        float tm[4];
        #pragma unroll
        for (int j = 0; j < 4; j++) {
            const int qg = q0 * 64 + w * 16 + lg * 4 + j;
            float mx = -1e30f;
            #pragma unroll
            for (int ct = 0; ct < 4; ct++) {
                const int kg = kt * 64 + ct * 16 + lq;
                float v = sacc[ct][j] * 0.125f;
                v = (kg <= qg) ? v : -1e30f;
                sacc[ct][j] = v;
                mx = fmaxf(mx, v);
            }
            #pragma unroll
            for (int d = 1; d < 16; d <<= 1) mx = fmaxf(mx, __shfl_xor(mx, d));
            tm[j] = mx;
        }
        #pragma unroll
        for (int j = 0; j < 4; j++) {
            const float nm = fmaxf(m_[j], tm[j]);
            const float so = __expf(m_[j] - nm);
            m_[j] = nm;
            float rs = 0.f;
            const int prow = lg * 4 + j;
            #pragma unroll
            for (int ct = 0; ct < 4; ct++) {
                const float p = __expf(sacc[ct][j] - nm);
                rs += p;
                const int byteoff = ((prow * 128) + (ct * 16 + lq) * 2) ^ ((prow & 7) << 4);
                *(unsigned short*)((char*)&pl[w][0] + byteoff) = f2b(p);
            }
            #pragma unroll
            for (int d = 1; d < 16; d <<= 1) rs += __shfl_xor(rs, d);
            s_[j] = s_[j] * so + rs;
            #pragma unroll
            for (int dt = 0; dt < 4; dt++) o_[dt][j] *= so;
        }
        asm volatile("s_waitcnt lgkmcnt(0)" ::: "memory");
        __builtin_amdgcn_sched_barrier(0);
        __builtin_amdgcn_s_setprio(1);
        #pragma unroll
        for (int c = 0; c < 2; c++) {
            bf16x8 pa = *(const bf16x8*)((const char*)&pl[w][0] +
                          ((lq * 128 + lg * 16 + 64 * c) ^ ((lq & 7) << 4)));
            #pragma unroll
            for (int dt = 0; dt < 4; dt++) {
                const int dd = dt * 16 + lq;
                bf16x8 bv = *(const bf16x8*)((const char*)&vt[cur][0] +
                              ((dd * 128 + lg * 16 + 64 * c) ^ SWZV(dd)));
                o_[dt] = __builtin_amdgcn_mfma_f32_16x16x32_bf16(pa, bv, o_[dt], 0, 0, 0);
            }
        }
        __builtin_amdgcn_s_setprio(0);
    };

    const int mymaxA = qA * 64 + w * 16 + 15;
    for (int kt = 0; kt < ntile; kt++) {
        bf16x8 kN[2], vN[2];
        const bool pre = (kt + 1 < ntile);
        if (pre) {
            #pragma unroll
            for (int p = 0; p < 2; p++) {
                const int row = srow + 32 * p;
                kN[p] = *(const bf16x8*)(K + base + (size_t)((kt + 1) * 64 + row) * ldq + scol);
                vN[p] = *(const bf16x8*)(V + base + (size_t)((kt + 1) * 64 + row) * ldq + scol);
            }
        }
        compute(qB, aqB, oB, mB, sB, kt);
        if (kt * 64 <= mymaxA) compute(qA, aqA, oA, mA, sA, kt);
        if (pre) {
            #pragma unroll
            for (int p = 0; p < 2; p++) {
                const int row = srow + 32 * p;
                *(bf16x8*)((char*)&ks[cur ^ 1][0] + ((row * 128 + scol * 2) ^ ((row & 7) << 4))) = kN[p];
                #pragma unroll
                for (int j2 = 0; j2 < 8; j2++) {
                    const int d = scol + j2;
                    *(unsigned short*)((char*)&vt[cur ^ 1][0] + ((d * 128 + row * 2) ^ SWZV(d))) =
                        (unsigned short)vN[p][j2];
                }
            }
        }
        __syncthreads();
        cur ^= 1;
    }

    #pragma unroll
    for (int j = 0; j < 4; j++) {
        const float invA = 1.f / sA[j];
        const float invB = 1.f / sB[j];
        const int rowA = qA * 64 + w * 16 + lg * 4 + j;
        const int rowB = qB * 64 + w * 16 + lg * 4 + j;
        unsigned short* opA = O + obase + (size_t)rowA * DM;
        unsigned short* opB = O + obase + (size_t)rowB * DM;
        #pragma unroll
        for (int dt = 0; dt < 4; dt++) {
            opA[dt * 16 + lq] = f2b(oA[dt][j] * invA);
            opB[dt * 16 + lq] = f2b(oB[dt][j] * invB);
        }
    }
}
#undef SWZV

// ---------------- fused knowledge: score + top-8 + softmax + V gather, one kernel ----------------
#define CE(a, b) { float hi_ = fmaxf(a, b), lo_ = fminf(a, b); a = hi_; b = lo_; }
__global__ void __launch_bounds__(512, 4) know_kernel(const unsigned short* __restrict__ Qmb,
                                                      const unsigned short* __restrict__ kKb,
                                                      const float* __restrict__ kV,
                                                      float* __restrict__ out) {
    const int t = threadIdx.x;
    const int w = t >> 6, l = t & 63, lq = l & 15, lg = l >> 4;
    const int tok0 = blockIdx.x * 16;
    __shared__ unsigned short ks[8][16 * 128];
    __shared__ float cs[16][64];

    bf16x8 aq[4];
    {
        const unsigned short* qp = Qmb + (size_t)(tok0 + lq) * 128 + lg * 8;
        #pragma unroll
        for (int c = 0; c < 4; c++) aq[c] = *(const bf16x8*)(qp + c * 32);
    }

    float L[4][8];
    #pragma unroll
    for (int j = 0; j < 4; j++)
        #pragma unroll
        for (int s = 0; s < 8; s++) L[j][s] = __uint_as_float(0xF2000000u | (unsigned)s);

    const unsigned short* gsrc = kKb + (((size_t)w * 2048) << 7) + l * 8;
    unsigned short* myks = &ks[w][0];

    bf16x8 vreg[4];
    #pragma unroll
    for (int p = 0; p < 4; p++) vreg[p] = *(const bf16x8*)(gsrc + p * 512);

    for (int t4 = 0; t4 < 32; t4++) {
        float B[4][4];
        #pragma unroll
        for (int sub = 0; sub < 4; sub++) {
            const int kt = t4 * 4 + sub;
            #pragma unroll
            for (int p = 0; p < 4; p++) {
                const int e = p * 512 + l * 8;
                const int row = e >> 7;
                *(bf16x8*)((char*)myks + ((e * 2) ^ ((row & 7) << 4))) = vreg[p];
            }
            if (kt < 127) {
                const unsigned short* src2 = gsrc + (size_t)(kt + 1) * 2048;
                #pragma unroll
                for (int p = 0; p < 4; p++) vreg[p] = *(const bf16x8*)(src2 + p * 512);
            }
            {
                const char* kb = (const char*)myks + lq * 256;
                const int sw = (lq & 7) << 4;
                f32x4 s = {0.f, 0.f, 0.f, 0.f};
                #pragma unroll
                for (int c = 0; c < 4; c++) {
                    bf16x8 bv = *(const bf16x8*)(kb + ((c * 64 + lg * 16) ^ sw));
                    s = __builtin_amdgcn_mfma_f32_16x16x32_bf16(aq[c], bv, s, 0, 0, 0);
                }
                const unsigned keyb = (unsigned)(w * 2048 + kt * 16 + lq);
                #pragma unroll
                for (int j = 0; j < 4; j++) {
                    unsigned u = __float_as_uint(s[j]);
                    B[j][sub] = __uint_as_float((u & 0xFFFFC000u) | keyb);
                }
            }
        }
        #pragma unroll
        for (int j = 0; j < 4; j++) {
            const float bmax = fmaxf(fmaxf(B[j][0], B[j][1]), fmaxf(B[j][2], B[j][3]));
            if (__any(bmax > L[j][7])) {
                CE(B[j][0], B[j][2]); CE(B[j][1], B[j][3]);
                CE(B[j][0], B[j][1]); CE(B[j][2], B[j][3]);
                CE(B[j][1], B[j][2]);
                L[j][4] = fmaxf(L[j][4], B[j][3]);
                L[j][5] = fmaxf(L[j][5], B[j][2]);
                L[j][6] = fmaxf(L[j][6], B[j][1]);
                L[j][7] = fmaxf(L[j][7], B[j][0]);
                CE(L[j][0], L[j][4]); CE(L[j][1], L[j][5]); CE(L[j][2], L[j][6]); CE(L[j][3], L[j][7]);
                CE(L[j][0], L[j][2]); CE(L[j][1], L[j][3]); CE(L[j][4], L[j][6]); CE(L[j][5], L[j][7]);
                CE(L[j][0], L[j][1]); CE(L[j][2], L[j][3]); CE(L[j][4], L[j][5]); CE(L[j][6], L[j][7]);
            }
        }
    }
    // cross-lq butterfly merge: 16 lq lanes -> wave top-8 per j
    #pragma unroll
    for (int j = 0; j < 4; j++) {
        #pragma unroll
        for (int d = 1; d < 16; d <<= 1) {
            float P[8];
            #pragma unroll
            for (int s = 0; s < 8; s++) P[s] = __shfl_xor(L[j][s], d);
            L[j][0] = fmaxf(L[j][0], P[7]);
            L[j][1] = fmaxf(L[j][1], P[6]);
            L[j][2] = fmaxf(L[j][2], P[5]);
            L[j][3] = fmaxf(L[j][3], P[4]);
            L[j][4] = fmaxf(L[j][4], P[3]);
            L[j][5] = fmaxf(L[j][5], P[2]);
            L[j][6] = fmaxf(L[j][6], P[1]);
            L[j][7] = fmaxf(L[j][7], P[0]);
            CE(L[j][0], L[j][4]); CE(L[j][1], L[j][5]); CE(L[j][2], L[j][6]); CE(L[j][3], L[j][7]);
            CE(L[j][0], L[j][2]); CE(L[j][1], L[j][3]); CE(L[j][4], L[j][6]); CE(L[j][5], L[j][7]);
            CE(L[j][0], L[j][1]); CE(L[j][2], L[j][3]); CE(L[j][4], L[j][5]); CE(L[j][6], L[j][7]);
        }
    }
    if (lq == 0) {
        #pragma unroll
        for (int j = 0; j < 4; j++) {
            const int tl = lg * 4 + j;
            #pragma unroll
            for (int ss = 0; ss < 8; ss++) cs[tl][w * 8 + ss] = L[j][ss];
        }
    }
    __syncthreads();

    // block merge + softmax + V gather: wave w handles local tokens 2w, 2w+1
    #pragma unroll
    for (int ti = 0; ti < 2; ti++) {
        const int tl = w * 2 + ti;
        float lv = cs[tl][l];
        float topv[8]; int topi[8];
        #pragma unroll
        for (int kk = 0; kk < 8; kk++) {
            float m = lv;
            #pragma unroll
            for (int d = 1; d < 64; d <<= 1) m = fmaxf(m, __shfl_xor(m, d));
            topv[kk] = m;
            topi[kk] = (int)(__float_as_uint(m) & 0x3FFFu);
            lv = (lv == m) ? -1e31f : lv;
        }
        const float mx = topv[0];
        float e[8]; float ssum = 0.f;
        #pragma unroll
        for (int kk = 0; kk < 8; kk++) { e[kk] = __expf(topv[kk] - mx); ssum += e[kk]; }
        const float inv = 1.f / ssum;

        float4 acc[4];
        #pragma unroll
        for (int ch = 0; ch < 4; ch++) acc[ch] = float4{0.f, 0.f, 0.f, 0.f};
        #pragma unroll
        for (int kk = 0; kk < 8; kk++) {
            const float wk = e[kk] * inv;
            const float* vp = kV + ((size_t)topi[kk] << 10);
            #pragma unroll
            for (int ch = 0; ch < 4; ch++) {
                float4 v = *(const float4*)(vp + ch * 256 + l * 4);
                acc[ch].x += wk * v.x; acc[ch].y += wk * v.y;
                acc[ch].z += wk * v.z; acc[ch].w += wk * v.w;
            }
        }
        float* op = out + ((size_t)(tok0 + tl) << 10);
        #pragma unroll
        for (int ch = 0; ch < 4; ch++) {
            float4 o = *(const float4*)(op + ch * 256 + l * 4);
            o.x += acc[ch].x; o.y += acc[ch].y; o.z += acc[ch].z; o.w += acc[ch].w;
            *(float4*)(op + ch * 256 + l * 4) = o;
        }
    }
}
#undef CE

extern "C" void kernel_launch(void* const* d_in, const int* in_sizes, int n_in,
                              void* d_out, int out_size, void* d_ws, size_t ws_size,
                              hipStream_t stream) {
    const float* x    = (const float*)d_in[0];
    const float* imp  = (const float*)d_in[1];
    const float* Wc   = (const float*)d_in[2];
    const float* WQr  = (const float*)d_in[3];
    const float* WKr  = (const float*)d_in[4];
    const float* WVr  = (const float*)d_in[5];
    const float* Wm   = (const float*)d_in[6];
    const float* cneu = (const float*)d_in[7];
    const float* epool= (const float*)d_in[8];
    const float* kK   = (const float*)d_in[9];
    const float* kV   = (const float*)d_in[10];
    const float* WO   = (const float*)d_in[11];
    const float* ln1s = (const float*)d_in[12];
    const float* ln1b = (const float*)d_in[13];
    const float* ln2s = (const float*)d_in[14];
    const float* ln2b = (const float*)d_in[15];
    float* out = (float*)d_out;

    float* ws = (float*)d_ws;
    size_t o = 0;
    unsigned short* n1h = (unsigned short*)(ws + o); o += (size_t)BD * SD * DM / 2;
    unsigned short* n1l = (unsigned short*)(ws + o); o += (size_t)BD * SD * DM / 2;
    float* lgt   = ws + o; o += (size_t)BD * SD * 192;
    float* partial = ws + o; o += (size_t)BD * 16 * 224;
    int*   ridx  = (int*)(ws + o); o += (size_t)BD * 5 * 8;
    float* rw    = ws + o; o += (size_t)BD * 5 * 8;
    unsigned short* WTh = (unsigned short*)(ws + o); o += (size_t)256 * 1024 / 2;
    unsigned short* WTl = (unsigned short*)(ws + o); o += (size_t)256 * 1024 / 2;
    unsigned short* scompT = (unsigned short*)(ws + o); o += (size_t)BD * RK * DM / 2;
    unsigned short* E3t = (unsigned short*)(ws + o); o += (size_t)BD * 3 * DM * RK / 2;
    unsigned short* hb  = (unsigned short*)(ws + o); o += (size_t)BD * SD * RK / 2;
    unsigned short* QKV16 = (unsigned short*)(ws + o); o += (size_t)BD * SD * 3072 / 2;
    unsigned short* attnb = (unsigned short*)(ws + o); o += (size_t)BD * SD * DM / 2;
    unsigned short* WOt = (unsigned short*)(ws + o); o += (size_t)DM * DM / 2;
    unsigned short* kKb = (unsigned short*)(ws + o); o += (size_t)NK * RK / 2;
    unsigned short* Qmb = (unsigned short*)(ws + o); o += (size_t)BD * SD * RK / 2;

    const int NTOK = BD * SD;
    const long long sE3 = (long long)3 * DM * RK;

    // fused prep (concatw | tcvt WO | cvt kK)
    prep_kernel<<<3328, 256, 0, stream>>>(Wc, WQr, WKr, WVr, Wm, WTh, WTl, WO, WOt, kK, kKb);

    // phase 1
    ln_kernel<<<NTOK, 256, 0, stream>>>(x, ln1s, ln1b, n1h, n1l);
    gemm_split<<<dim3(3, NTOK / 64), 256, 0, stream>>>(n1h, n1l, WTh, WTl, lgt, 192, DM);
    softpref_red<<<dim3(BD, 16), 256, 0, stream>>>(lgt, imp, partial);
    topk_kernel<<<1, 64, 0, stream>>>(partial, ridx, rw, 0, 4);
    combine_all_kernel<<<1024, 256, 0, stream>>>(cneu, epool, ridx, rw, scompT, E3t);
    gemm_h<<<dim3(1, SD / 64, BD), 256, 0, stream>>>(n1h, scompT, hb,
        DM, (long long)SD * DM, (long long)RK * DM, (long long)SD * RK);
    gemm_bf16<1, 0><<<dim3(24, 8, BD), 256, 0, stream>>>(hb, E3t, nullptr, QKV16,
        SD, 3072, RK, (long long)SD * RK, sE3, (long long)SD * 3072);
    attn_mfma_kernel<<<dim3(8, NH, BD), 256, 0, stream>>>(QKV16, QKV16 + 1024, QKV16 + 2048,
        attnb, 3072);
    gemm_bf16<0, 1><<<dim3(8, 64, 1), 256, 0, stream>>>(attnb, WOt, x, out,
        NTOK, DM, DM, 0, 0, 0);

    // phase 2
    ln_kernel<<<NTOK, 256, 0, stream>>>(out, ln2s, ln2b, n1h, n1l);
    gemm_split_sm2<<<NTOK / 64, 256, 0, stream>>>(n1h, n1l,
        WTh + (size_t)192 * 1024, WTl + (size_t)192 * 1024, imp, partial);
    topk_kernel<<<1, 64, 0, stream>>>(partial, ridx, rw, 4, 1);
    combine_t_kernel<<<dim3(2, 16, BD), 256, 0, stream>>>(cneu, ridx, rw, 4, 8, scompT, DM, RK,
        (long long)DM * RK);
    gemm_h<<<dim3(1, SD / 64, BD), 256, 0, stream>>>(n1h, scompT, Qmb,
        DM, (long long)SD * DM, (long long)RK * DM, (long long)SD * RK);
    know_kernel<<<NTOK / 16, 512, 0, stream>>>(Qmb, kKb, kV, out);
}

// Round 18
// 572.883 us; speedup vs baseline: 1.0518x; 1.0274x over previous
//
#include <hip/hip_runtime.h>
#include <hip/hip_bf16.h>

#define BD 8
#define SD 1024
#define DM 1024
#define NH 16
#define DH 64
#define RK 128
#define NK 16384

typedef __attribute__((ext_vector_type(8))) short bf16x8;
typedef __attribute__((ext_vector_type(4))) float f32x4;

__device__ __forceinline__ unsigned short f2b(float f) {
    unsigned u = __float_as_uint(f);
    unsigned r = (u + 0x7FFFu + ((u >> 16) & 1u)) >> 16;
    return (unsigned short)r;
}
__device__ __forceinline__ float b2f(unsigned short h) {
    return __uint_as_float(((unsigned)h) << 16);
}

// ---------------- LayerNorm: bf16 hi/lo outputs ----------------
__global__ void __launch_bounds__(256) ln_kernel(const float* __restrict__ x,
                                                 const float* __restrict__ sc,
                                                 const float* __restrict__ bi,
                                                 unsigned short* __restrict__ outh,
                                                 unsigned short* __restrict__ outl) {
    const int tok = blockIdx.x;
    __shared__ float xs[DM];
    __shared__ float red[256];
    const float* xp = x + (size_t)tok * DM;
    float s = 0.f;
    for (int i = threadIdx.x; i < DM; i += 256) { float v = xp[i]; xs[i] = v; s += v; }
    red[threadIdx.x] = s; __syncthreads();
    for (int st = 128; st; st >>= 1) { if (threadIdx.x < st) red[threadIdx.x] += red[threadIdx.x + st]; __syncthreads(); }
    float mu = red[0] * (1.f / DM);
    __syncthreads();
    float vs = 0.f;
    for (int i = threadIdx.x; i < DM; i += 256) { float d = xs[i] - mu; vs += d * d; }
    red[threadIdx.x] = vs; __syncthreads();
    for (int st = 128; st; st >>= 1) { if (threadIdx.x < st) red[threadIdx.x] += red[threadIdx.x + st]; __syncthreads(); }
    float rs = rsqrtf(red[0] * (1.f / DM) + 1e-5f);
    for (int i = threadIdx.x; i < DM; i += 256) {
        float v = (xs[i] - mu) * rs * sc[i] + bi[i];
        unsigned short h = f2b(v);
        outh[(size_t)tok * DM + i] = h;
        outl[(size_t)tok * DM + i] = f2b(v - b2f(h));
    }
}

// ---------------- fused prep: concatw (0..1023) | tcvt WO (1024..1279) | cvt kK (1280..3327) ----------------
__global__ void __launch_bounds__(256) prep_kernel(const float* __restrict__ Wc,
                                                   const float* __restrict__ WQr,
                                                   const float* __restrict__ WKr,
                                                   const float* __restrict__ WVr,
                                                   const float* __restrict__ Wm,
                                                   unsigned short* __restrict__ WTh,
                                                   unsigned short* __restrict__ WTl,
                                                   const float* __restrict__ WO,
                                                   unsigned short* __restrict__ WOt,
                                                   const float* __restrict__ kK,
                                                   unsigned short* __restrict__ kKb) {
    __shared__ float ls[64][65];
    const int t = threadIdx.x;
    const int bid = blockIdx.x;
    if (bid < 1024) {
        const int i = bid * 256 + t;
        const int c = i >> 10, d = i & 1023;
        float v = 0.f;
        if (c < 64)       v = Wc[d * 64 + c];
        else if (c < 96)  v = WQr[d * 32 + c - 64];
        else if (c < 128) v = WKr[d * 32 + c - 96];
        else if (c < 160) v = WVr[d * 32 + c - 128];
        else if (c >= 192) v = Wm[d * 64 + c - 192];
        unsigned short h = f2b(v);
        WTh[i] = h;
        WTl[i] = f2b(v - b2f(h));
    } else if (bid < 1280) {
        const int bz = bid - 1024;
        const int r0 = (bz >> 4) * 64, c0 = (bz & 15) * 64;
        #pragma unroll
        for (int p = 0; p < 16; p++) {
            const int e = p * 256 + t;
            const int r = e >> 6, c = e & 63;
            ls[r][c] = WO[(size_t)(r0 + r) * DM + c0 + c];
        }
        __syncthreads();
        #pragma unroll
        for (int p = 0; p < 16; p++) {
            const int e = p * 256 + t;
            const int c = e >> 6, r = e & 63;
            WOt[(size_t)(c0 + c) * DM + r0 + r] = f2b(ls[r][c]);
        }
    } else {
        const int i = (bid - 1280) * 256 + t;
        const float scale = 0.0883883476483184f;
        float4 v = ((const float4*)kK)[i];
        unsigned r0 = (unsigned)f2b(v.x * scale) | ((unsigned)f2b(v.y * scale) << 16);
        unsigned r1 = (unsigned)f2b(v.z * scale) | ((unsigned)f2b(v.w * scale) << 16);
        uint2 o; o.x = r0; o.y = r1;
        ((uint2*)kKb)[i] = o;
    }
}

// ---------------- split-bf16 logits GEMM, BM=64 (phase 1) ----------------
__global__ void __launch_bounds__(256) gemm_split(const unsigned short* __restrict__ Ah,
                                                  const unsigned short* __restrict__ Al,
                                                  const unsigned short* __restrict__ Bh,
                                                  const unsigned short* __restrict__ Bl,
                                                  float* __restrict__ C,
                                                  int N, int K) {
    const int row0 = blockIdx.y * 64, col0 = blockIdx.x * 64;
    const int t = threadIdx.x;
    const int w = t >> 6, l = t & 63, lq = l & 15, lg = l >> 4;
    __shared__ unsigned short sAh[64 * 64];
    __shared__ unsigned short sAl[64 * 64];
    __shared__ unsigned short sBh[64 * 64];
    __shared__ unsigned short sBl[64 * 64];
    f32x4 acc[4];
    #pragma unroll
    for (int ni = 0; ni < 4; ni++) acc[ni] = f32x4{0.f, 0.f, 0.f, 0.f};

    for (int k0 = 0; k0 < K; k0 += 64) {
        __syncthreads();
        #pragma unroll
        for (int p = 0; p < 2; p++) {
            const int e = t * 8 + p * 2048;
            const int row = e >> 6, col = e & 63;
            const int sw = (e * 2) ^ ((row & 7) << 4);
            *(bf16x8*)((char*)sAh + sw) = *(const bf16x8*)(Ah + (size_t)(row0 + row) * K + k0 + col);
            *(bf16x8*)((char*)sAl + sw) = *(const bf16x8*)(Al + (size_t)(row0 + row) * K + k0 + col);
            *(bf16x8*)((char*)sBh + sw) = *(const bf16x8*)(Bh + (size_t)(col0 + row) * K + k0 + col);
            *(bf16x8*)((char*)sBl + sw) = *(const bf16x8*)(Bl + (size_t)(col0 + row) * K + k0 + col);
        }
        __syncthreads();
        #pragma unroll
        for (int kk = 0; kk < 2; kk++) {
            bf16x8 ah, al, bh[4], bl[4];
            {
                const int r = w * 16 + lq;
                const int off = (r * 128 + lg * 16 + kk * 64) ^ ((r & 7) << 4);
                ah = *(const bf16x8*)((const char*)sAh + off);
                al = *(const bf16x8*)((const char*)sAl + off);
            }
            #pragma unroll
            for (int ni = 0; ni < 4; ni++) {
                const int r = ni * 16 + lq;
                const int off = (r * 128 + lg * 16 + kk * 64) ^ ((r & 7) << 4);
                bh[ni] = *(const bf16x8*)((const char*)sBh + off);
                bl[ni] = *(const bf16x8*)((const char*)sBl + off);
            }
            #pragma unroll
            for (int ni = 0; ni < 4; ni++) {
                acc[ni] = __builtin_amdgcn_mfma_f32_16x16x32_bf16(ah, bh[ni], acc[ni], 0, 0, 0);
                acc[ni] = __builtin_amdgcn_mfma_f32_16x16x32_bf16(ah, bl[ni], acc[ni], 0, 0, 0);
                acc[ni] = __builtin_amdgcn_mfma_f32_16x16x32_bf16(al, bh[ni], acc[ni], 0, 0, 0);
            }
        }
    }
    #pragma unroll
    for (int j = 0; j < 4; j++) {
        const int row = row0 + w * 16 + lg * 4 + j;
        #pragma unroll
        for (int ni = 0; ni < 4; ni++)
            C[(size_t)row * N + col0 + ni * 16 + lq] = acc[ni][j];
    }
}

// ---------------- fused phase-2 logits GEMM + softmax + chunk reduce (N=64) ----------------
__global__ void __launch_bounds__(256) gemm_split_sm2(const unsigned short* __restrict__ Ah,
                                                      const unsigned short* __restrict__ Al,
                                                      const unsigned short* __restrict__ Bh,
                                                      const unsigned short* __restrict__ Bl,
                                                      const float* __restrict__ imp,
                                                      float* __restrict__ partial) {
    const int row0 = blockIdx.x * 64;
    const int K = DM;
    const int t = threadIdx.x;
    const int w = t >> 6, l = t & 63, lq = l & 15, lg = l >> 4;
    __shared__ unsigned short sAh[64 * 64];
    __shared__ unsigned short sAl[64 * 64];
    __shared__ unsigned short sBh[64 * 64];
    __shared__ unsigned short sBl[64 * 64];
    __shared__ float wsm[64][65];
    f32x4 acc[4];
    #pragma unroll
    for (int ni = 0; ni < 4; ni++) acc[ni] = f32x4{0.f, 0.f, 0.f, 0.f};

    for (int k0 = 0; k0 < K; k0 += 64) {
        __syncthreads();
        #pragma unroll
        for (int p = 0; p < 2; p++) {
            const int e = t * 8 + p * 2048;
            const int row = e >> 6, col = e & 63;
            const int sw = (e * 2) ^ ((row & 7) << 4);
            *(bf16x8*)((char*)sAh + sw) = *(const bf16x8*)(Ah + (size_t)(row0 + row) * K + k0 + col);
            *(bf16x8*)((char*)sAl + sw) = *(const bf16x8*)(Al + (size_t)(row0 + row) * K + k0 + col);
            *(bf16x8*)((char*)sBh + sw) = *(const bf16x8*)(Bh + (size_t)(row) * K + k0 + col);
            *(bf16x8*)((char*)sBl + sw) = *(const bf16x8*)(Bl + (size_t)(row) * K + k0 + col);
        }
        __syncthreads();
        #pragma unroll
        for (int kk = 0; kk < 2; kk++) {
            bf16x8 ah, al, bh[4], bl[4];
            {
                const int r = w * 16 + lq;
                const int off = (r * 128 + lg * 16 + kk * 64) ^ ((r & 7) << 4);
                ah = *(const bf16x8*)((const char*)sAh + off);
                al = *(const bf16x8*)((const char*)sAl + off);
            }
            #pragma unroll
            for (int ni = 0; ni < 4; ni++) {
                const int r = ni * 16 + lq;
                const int off = (r * 128 + lg * 16 + kk * 64) ^ ((r & 7) << 4);
                bh[ni] = *(const bf16x8*)((const char*)sBh + off);
                bl[ni] = *(const bf16x8*)((const char*)sBl + off);
            }
            #pragma unroll
            for (int ni = 0; ni < 4; ni++) {
                acc[ni] = __builtin_amdgcn_mfma_f32_16x16x32_bf16(ah, bh[ni], acc[ni], 0, 0, 0);
                acc[ni] = __builtin_amdgcn_mfma_f32_16x16x32_bf16(ah, bl[ni], acc[ni], 0, 0, 0);
                acc[ni] = __builtin_amdgcn_mfma_f32_16x16x32_bf16(al, bh[ni], acc[ni], 0, 0, 0);
            }
        }
    }
    #pragma unroll
    for (int j = 0; j < 4; j++) {
        float mx = fmaxf(fmaxf(acc[0][j], acc[1][j]), fmaxf(acc[2][j], acc[3][j]));
        #pragma unroll
        for (int d = 1; d < 16; d <<= 1) mx = fmaxf(mx, __shfl_xor(mx, d));
        float e0 = __expf(acc[0][j] - mx), e1 = __expf(acc[1][j] - mx);
        float e2 = __expf(acc[2][j] - mx), e3 = __expf(acc[3][j] - mx);
        float ss = e0 + e1 + e2 + e3;
        #pragma unroll
        for (int d = 1; d < 16; d <<= 1) ss += __shfl_xor(ss, d);
        const int rl = w * 16 + lg * 4 + j;
        const float scl = imp[row0 + rl] / ss;
        wsm[rl][lq]      = e0 * scl;
        wsm[rl][16 + lq] = e1 * scl;
        wsm[rl][32 + lq] = e2 * scl;
        wsm[rl][48 + lq] = e3 * scl;
    }
    __syncthreads();
    if (t < 64) {
        float s = 0.f;
        for (int k = 0; k < 64; k++) s += wsm[k][t];
        const int b = row0 >> 10, chunk = (row0 >> 6) & 15;
        partial[((size_t)(b * 16 + chunk)) * 224 + 160 + t] = s;
    }
}

// ---------------- fused phase-1 softmax + chunk reduce ----------------
__global__ void __launch_bounds__(256) softpref_red(const float* __restrict__ lgt,
                                                    const float* __restrict__ imp,
                                                    float* __restrict__ partial) {
    const int b = blockIdx.x, chunk = blockIdx.y;
    __shared__ float wp[64][161];
    const int t = threadIdx.x;
    const int tl = t >> 2, sg = t & 3;
    const int tok = b * SD + chunk * 64 + tl;
    const int o = (sg == 0) ? 0 : (64 + 32 * (sg - 1));
    const int n = (sg == 0) ? 64 : 32;
    const float* lp = lgt + (size_t)tok * 192 + o;
    float m = -1e30f;
    for (int i = 0; i < n; i++) m = fmaxf(m, lp[i]);
    float ss = 0.f;
    for (int i = 0; i < n; i++) ss += __expf(lp[i] - m);
    const float scl = imp[tok] / ss;
    for (int i = 0; i < n; i++) wp[tl][o + i] = __expf(lp[i] - m) * scl;
    __syncthreads();
    if (t < 160) {
        float s = 0.f;
        for (int k = 0; k < 64; k++) s += wp[k][t];
        partial[((size_t)(b * 16 + chunk)) * 224 + t] = s;
    }
}

// ---------------- top-k sparsify + renormalize (sums 16 chunk partials) ----------------
__global__ void topk_kernel(const float* __restrict__ partial,
                            int* __restrict__ ridx, float* __restrict__ rw,
                            int r0, int nr) {
    __shared__ float dv[40][65];
    const int t = threadIdx.x;
    if (t >= BD * nr) return;
    const int b = t / nr, r = r0 + (t % nr);
    const int offs[5] = {0, 64, 96, 128, 160};
    const int ns[5]   = {64, 32, 32, 32, 64};
    const int ks[5]   = {8, 4, 4, 4, 8};
    const int n = ns[r], k = ks[r], off = offs[r];
    for (int i = 0; i < n; i++) {
        float s = 0.f;
        for (int c = 0; c < 16; c++) s += partial[((size_t)(b * 16 + c)) * 224 + off + i];
        dv[t][i] = s;
    }
    unsigned long long mask = 0;
    float vals[8]; int idxs[8];
    float ssum = 0.f;
    for (int kk = 0; kk < k; kk++) {
        float best = -1e30f; int bi = 0;
        for (int i = 0; i < n; i++)
            if (!((mask >> i) & 1ull) && dv[t][i] > best) { best = dv[t][i]; bi = i; }
        mask |= 1ull << bi;
        vals[kk] = best; idxs[kk] = bi; ssum += best;
    }
    float inv = 1.f / (ssum + 1e-8f);
    for (int kk = 0; kk < 8; kk++) {
        ridx[(b * 5 + r) * 8 + kk] = (kk < k) ? idxs[kk] : 0;
        rw[(b * 5 + r) * 8 + kk]   = (kk < k) ? vals[kk] * inv : 0.f;
    }
}

// ---------------- fused mixtures: flat grid, blocks 0..255 scompT, 256..1023 E3t ----------------
__global__ void __launch_bounds__(256) combine_all_kernel(const float* __restrict__ cneu,
                                                          const float* __restrict__ epool,
                                                          const int* __restrict__ ridx,
                                                          const float* __restrict__ rw,
                                                          unsigned short* __restrict__ scompT,
                                                          unsigned short* __restrict__ E3t) {
    __shared__ float ls[64][65];
    const int t = threadIdx.x;
    const int bid = blockIdx.x;
    const float* pool;
    int b, router, r0, c0, Rp, Cp;
    unsigned short* op;
    if (bid < 256) {
        b = bid >> 5;
        const int rem = bid & 31;
        c0 = (rem & 1) * 64; r0 = (rem >> 1) * 64;
        Rp = DM; Cp = RK; router = 0; pool = cneu;
        op = scompT + (size_t)b * DM * RK;
    } else {
        const int e = bid - 256;
        const int z = e >> 5;
        const int rem = e & 31;
        c0 = (rem & 15) * 64; r0 = (rem >> 4) * 64;
        b = z & 7; router = 1 + (z >> 3);
        Rp = RK; Cp = DM; pool = epool;
        op = E3t + (size_t)b * 3 * DM * RK + (size_t)(router - 1) * DM * RK;
    }
    const int* ii = ridx + (b * 5 + router) * 8;
    const float* ww = rw + (b * 5 + router) * 8;
    const int kc = (router == 0) ? 8 : 4;
    const int rr = t >> 4, cc = (t & 15) * 4;
    #pragma unroll
    for (int p = 0; p < 4; p++) {
        const int r = rr + p * 16;
        float4 acc = {0.f, 0.f, 0.f, 0.f};
        for (int kk = 0; kk < kc; kk++) {
            const float w = ww[kk];
            float4 v = *(const float4*)&pool[((size_t)ii[kk] * Rp + r0 + r) * Cp + c0 + cc];
            acc.x += w * v.x; acc.y += w * v.y; acc.z += w * v.z; acc.w += w * v.w;
        }
        ls[r][cc] = acc.x; ls[r][cc + 1] = acc.y; ls[r][cc + 2] = acc.z; ls[r][cc + 3] = acc.w;
    }
    __syncthreads();
    #pragma unroll
    for (int q = 0; q < 2; q++) {
        const int c = (t >> 3) + q * 32;
        const int r8 = (t & 7) * 8;
        union { unsigned short s[8]; bf16x8 v; } u;
        #pragma unroll
        for (int j = 0; j < 8; j++) u.s[j] = f2b(ls[r8 + j][c]);
        *(bf16x8*)(op + (size_t)(c0 + c) * Rp + r0 + r8) = u.v;
    }
}

// ---------------- single combine (phase 2 scompT) ----------------
__global__ void __launch_bounds__(256) combine_t_kernel(const float* __restrict__ pool,
                                                        const int* __restrict__ ridx,
                                                        const float* __restrict__ rw,
                                                        int router, int kc,
                                                        unsigned short* __restrict__ outT,
                                                        int Rp, int Cp, long long sOut) {
    const int b = blockIdx.z;
    const int r0 = blockIdx.y * 64, c0 = blockIdx.x * 64;
    __shared__ float ls[64][65];
    const int* ii = ridx + (b * 5 + router) * 8;
    const float* ww = rw + (b * 5 + router) * 8;
    const int t = threadIdx.x;
    const int rr = t >> 4, cc = (t & 15) * 4;
    #pragma unroll
    for (int p = 0; p < 4; p++) {
        const int r = rr + p * 16;
        float4 acc = {0.f, 0.f, 0.f, 0.f};
        for (int kk = 0; kk < kc; kk++) {
            const float w = ww[kk];
            float4 v = *(const float4*)&pool[((size_t)ii[kk] * Rp + r0 + r) * Cp + c0 + cc];
            acc.x += w * v.x; acc.y += w * v.y; acc.z += w * v.z; acc.w += w * v.w;
        }
        ls[r][cc] = acc.x; ls[r][cc + 1] = acc.y; ls[r][cc + 2] = acc.z; ls[r][cc + 3] = acc.w;
    }
    __syncthreads();
    unsigned short* op = outT + (size_t)b * sOut;
    #pragma unroll
    for (int q = 0; q < 2; q++) {
        const int c = (t >> 3) + q * 32;
        const int r8 = (t & 7) * 8;
        union { unsigned short s[8]; bf16x8 v; } u;
        #pragma unroll
        for (int j = 0; j < 8; j++) u.s[j] = f2b(ls[r8 + j][c]);
        *(bf16x8*)(op + (size_t)(c0 + c) * Rp + r0 + r8) = u.v;
    }
}

// ---------------- bf16 MFMA GEMM: C = A[M][K] @ Bt[N][K]^T (+X), 128x128 tile ----------------
template<int OUTB, int HASX>
__global__ void __launch_bounds__(256) gemm_bf16(const unsigned short* __restrict__ A,
                                                 const unsigned short* __restrict__ Bt,
                                                 const float* __restrict__ X,
                                                 void* __restrict__ Cv,
                                                 int M, int N, int K,
                                                 long long sA, long long sB, long long sC) {
    const int bz = blockIdx.z;
    const unsigned short* Ab = A + (size_t)bz * sA;
    const unsigned short* Btb = Bt + (size_t)bz * sB;
    const int row0 = blockIdx.y * 128, col0 = blockIdx.x * 128;
    const int t = threadIdx.x;
    const int w = t >> 6, l = t & 63, lq = l & 15, lg = l >> 4;
    const int wr = w >> 1, wc = w & 1;
    __shared__ unsigned short As[128 * 64];
    __shared__ unsigned short Bs[128 * 64];
    f32x4 acc[4][4];
    #pragma unroll
    for (int mi = 0; mi < 4; mi++)
        #pragma unroll
        for (int ni = 0; ni < 4; ni++) acc[mi][ni] = f32x4{0.f, 0.f, 0.f, 0.f};

    for (int k0 = 0; k0 < K; k0 += 64) {
        __syncthreads();
        #pragma unroll
        for (int p = 0; p < 4; p++) {
            const int e = t * 8 + p * 2048;
            const int row = e >> 6, col = e & 63;
            bf16x8 va = *(const bf16x8*)(Ab + (size_t)(row0 + row) * K + k0 + col);
            *(bf16x8*)((char*)As + ((row * 128 + col * 2) ^ ((row & 7) << 4))) = va;
            bf16x8 vb = *(const bf16x8*)(Btb + (size_t)(col0 + row) * K + k0 + col);
            *(bf16x8*)((char*)Bs + ((row * 128 + col * 2) ^ ((row & 7) << 4))) = vb;
        }
        __syncthreads();
        #pragma unroll
        for (int kk = 0; kk < 2; kk++) {
            bf16x8 af[4], bg[4];
            #pragma unroll
            for (int mi = 0; mi < 4; mi++) {
                const int r = wr * 64 + mi * 16 + lq;
                af[mi] = *(const bf16x8*)((const char*)As + ((r * 128 + lg * 16 + kk * 64) ^ ((r & 7) << 4)));
            }
            #pragma unroll
            for (int ni = 0; ni < 4; ni++) {
                const int r = wc * 64 + ni * 16 + lq;
                bg[ni] = *(const bf16x8*)((const char*)Bs + ((r * 128 + lg * 16 + kk * 64) ^ ((r & 7) << 4)));
            }
            #pragma unroll
            for (int mi = 0; mi < 4; mi++)
                #pragma unroll
                for (int ni = 0; ni < 4; ni++)
                    acc[mi][ni] = __builtin_amdgcn_mfma_f32_16x16x32_bf16(af[mi], bg[ni], acc[mi][ni], 0, 0, 0);
        }
    }
    #pragma unroll
    for (int mi = 0; mi < 4; mi++) {
        #pragma unroll
        for (int j = 0; j < 4; j++) {
            const int row = row0 + wr * 64 + mi * 16 + lg * 4 + j;
            #pragma unroll
            for (int ni = 0; ni < 4; ni++) {
                const int col = col0 + wc * 64 + ni * 16 + lq;
                float v = acc[mi][ni][j];
                if (HASX) v += X[(size_t)row * N + col];
                if (OUTB) ((unsigned short*)Cv)[(size_t)bz * sC + (size_t)row * N + col] = f2b(v);
                else      ((float*)Cv)[(size_t)bz * sC + (size_t)row * N + col] = v;
            }
        }
    }
}

// ---------------- narrow GEMM for h/Qm: BM=64, N=128 fixed, bf16 out ----------------
__global__ void __launch_bounds__(256) gemm_h(const unsigned short* __restrict__ A,
                                              const unsigned short* __restrict__ Bt,
                                              unsigned short* __restrict__ C,
                                              int K,
                                              long long sA, long long sB, long long sC) {
    const int bz = blockIdx.z;
    const unsigned short* Ab = A + (size_t)bz * sA;
    const unsigned short* Btb = Bt + (size_t)bz * sB;
    const int row0 = blockIdx.y * 64;
    const int t = threadIdx.x;
    const int w = t >> 6, l = t & 63, lq = l & 15, lg = l >> 4;
    __shared__ unsigned short As[64 * 64];
    __shared__ unsigned short Bs[128 * 64];
    f32x4 acc[8];
    #pragma unroll
    for (int ni = 0; ni < 8; ni++) acc[ni] = f32x4{0.f, 0.f, 0.f, 0.f};

    for (int k0 = 0; k0 < K; k0 += 64) {
        __syncthreads();
        #pragma unroll
        for (int p = 0; p < 2; p++) {
            const int e = t * 8 + p * 2048;
            const int row = e >> 6, col = e & 63;
            bf16x8 va = *(const bf16x8*)(Ab + (size_t)(row0 + row) * K + k0 + col);
            *(bf16x8*)((char*)As + ((row * 128 + col * 2) ^ ((row & 7) << 4))) = va;
        }
        #pragma unroll
        for (int p = 0; p < 4; p++) {
            const int e = t * 8 + p * 2048;
            const int row = e >> 6, col = e & 63;
            bf16x8 vb = *(const bf16x8*)(Btb + (size_t)row * K + k0 + col);
            *(bf16x8*)((char*)Bs + ((row * 128 + col * 2) ^ ((row & 7) << 4))) = vb;
        }
        __syncthreads();
        #pragma unroll
        for (int kk = 0; kk < 2; kk++) {
            const int ra = w * 16 + lq;
            bf16x8 af = *(const bf16x8*)((const char*)As + ((ra * 128 + lg * 16 + kk * 64) ^ ((ra & 7) << 4)));
            #pragma unroll
            for (int ni = 0; ni < 8; ni++) {
                const int r = ni * 16 + lq;
                bf16x8 bg = *(const bf16x8*)((const char*)Bs + ((r * 128 + lg * 16 + kk * 64) ^ ((r & 7) << 4)));
                acc[ni] = __builtin_amdgcn_mfma_f32_16x16x32_bf16(af, bg, acc[ni], 0, 0, 0);
            }
        }
    }
    #pragma unroll
    for (int j = 0; j < 4; j++) {
        const int row = row0 + w * 16 + lg * 4 + j;
        #pragma unroll
        for (int ni = 0; ni < 8; ni++)
            C[(size_t)bz * sC + (size_t)row * 128 + ni * 16 + lq] = f2b(acc[ni][j]);
    }
}

// ---------------- flash attention: paired q-tiles, dbuf K/V, strided QKV input ----------------
#define SWZV(d) (((((d) >> 1) ^ ((d) >> 3)) & 7) << 4)
__global__ void __launch_bounds__(256) attn_mfma_kernel(const unsigned short* __restrict__ Q,
                                                        const unsigned short* __restrict__ K,
                                                        const unsigned short* __restrict__ V,
                                                        unsigned short* __restrict__ O,
                                                        int ldq) {
    const int qt = blockIdx.x, hh = blockIdx.y, b = blockIdx.z;
    const int t = threadIdx.x;
    const int w = t >> 6, l = t & 63, lq = l & 15, lg = l >> 4;

    __shared__ unsigned short ks[2][64 * 64];
    __shared__ unsigned short vt[2][64 * 64];
    __shared__ unsigned short pl[4][16 * 64];

    const size_t base = (size_t)b * SD * ldq + (size_t)hh * DH;
    const size_t obase = (size_t)b * SD * DM + (size_t)hh * DH;
    const int qA = qt;
    const int qB = 15 - qt;

    bf16x8 aqA[2], aqB[2];
    {
        const unsigned short* qp = Q + base + (size_t)(qA * 64 + w * 16 + lq) * ldq + lg * 8;
        aqA[0] = *(const bf16x8*)qp; aqA[1] = *(const bf16x8*)(qp + 32);
        const unsigned short* qp2 = Q + base + (size_t)(qB * 64 + w * 16 + lq) * ldq + lg * 8;
        aqB[0] = *(const bf16x8*)qp2; aqB[1] = *(const bf16x8*)(qp2 + 32);
    }

    f32x4 oA[4], oB[4];
    #pragma unroll
    for (int dt = 0; dt < 4; dt++) { oA[dt] = f32x4{0.f,0.f,0.f,0.f}; oB[dt] = f32x4{0.f,0.f,0.f,0.f}; }
    float mA[4] = {-1e30f,-1e30f,-1e30f,-1e30f}, sA[4] = {0.f,0.f,0.f,0.f};
    float mB[4] = {-1e30f,-1e30f,-1e30f,-1e30f}, sB[4] = {0.f,0.f,0.f,0.f};

    const int ntile = 16 - qt;
    const int srow = t >> 3;
    const int scol = (t & 7) * 8;

    int cur = 0;

    #pragma unroll
    for (int p = 0; p < 2; p++) {
        const int row = srow + 32 * p;
        bf16x8 kv = *(const bf16x8*)(K + base + (size_t)row * ldq + scol);
        *(bf16x8*)((char*)&ks[0][0] + ((row * 128 + scol * 2) ^ ((row & 7) << 4))) = kv;
        bf16x8 vv = *(const bf16x8*)(V + base + (size_t)row * ldq + scol);
        #pragma unroll
        for (int j2 = 0; j2 < 8; j2++) {
            const int d = scol + j2;
            *(unsigned short*)((char*)&vt[0][0] + ((d * 128 + row * 2) ^ SWZV(d))) = (unsigned short)vv[j2];
        }
    }
    __syncthreads();

    auto compute = [&](int q0, const bf16x8* aq, f32x4* o_, float* m_, float* s_, int kt) {
        const f32x4 zero4 = {0.f, 0.f, 0.f, 0.f};
        f32x4 sacc[4];
        __builtin_amdgcn_s_setprio(1);
        #pragma unroll
        for (int ct = 0; ct < 4; ct++) {
            const int krow = ct * 16 + lq;
            bf16x8 b0 = *(const bf16x8*)((const char*)&ks[cur][0] + ((krow * 128 + lg * 16) ^ ((lq & 7) << 4)));
            bf16x8 b1 = *(const bf16x8*)((const char*)&ks[cur][0] + ((krow * 128 + lg * 16 + 64) ^ ((lq & 7) << 4)));
            f32x4 s = __builtin_amdgcn_mfma_f32_16x16x32_bf16(aq[0], b0, zero4, 0, 0, 0);
            s = __builtin_amdgcn_mfma_f32_16x16x32_bf16(aq[1], b1, s, 0, 0, 0);
            sacc[ct] = s;
        }
        __builtin_amdgcn_s_setprio(0);
        float tm[4];
        #pragma unroll
        for (int j = 0; j < 4; j++) {
            const int qg = q0 * 64 + w * 16 + lg * 4 + j;
            float mx = -1e30f;
            #pragma unroll
            for (int ct = 0; ct < 4; ct++) {
                const int kg = kt * 64 + ct * 16 + lq;
                float v = sacc[ct][j] * 0.125f;
                v = (kg <= qg) ? v : -1e30f;
                sacc[ct][j] = v;
                mx = fmaxf(mx, v);
            }
            #pragma unroll
            for (int d = 1; d < 16; d <<= 1) mx = fmaxf(mx, __shfl_xor(mx, d));
            tm[j] = mx;
        }
        #pragma unroll
        for (int j = 0; j < 4; j++) {
            const float nm = fmaxf(m_[j], tm[j]);
            const float so = __expf(m_[j] - nm);
            m_[j] = nm;
            float rs = 0.f;
            const int prow = lg * 4 + j;
            #pragma unroll
            for (int ct = 0; ct < 4; ct++) {
                const float p = __expf(sacc[ct][j] - nm);
                rs += p;
                const int byteoff = ((prow * 128) + (ct * 16 + lq) * 2) ^ ((prow & 7) << 4);
                *(unsigned short*)((char*)&pl[w][0] + byteoff) = f2b(p);
            }
            #pragma unroll
            for (int d = 1; d < 16; d <<= 1) rs += __shfl_xor(rs, d);
            s_[j] = s_[j] * so + rs;
            #pragma unroll
            for (int dt = 0; dt < 4; dt++) o_[dt][j] *= so;
        }
        asm volatile("s_waitcnt lgkmcnt(0)" ::: "memory");
        __builtin_amdgcn_sched_barrier(0);
        __builtin_amdgcn_s_setprio(1);
        #pragma unroll
        for (int c = 0; c < 2; c++) {
            bf16x8 pa = *(const bf16x8*)((const char*)&pl[w][0] +
                          ((lq * 128 + lg * 16 + 64 * c) ^ ((lq & 7) << 4)));
            #pragma unroll
            for (int dt = 0; dt < 4; dt++) {
                const int dd = dt * 16 + lq;
                bf16x8 bv = *(const bf16x8*)((const char*)&vt[cur][0] +
                              ((dd * 128 + lg * 16 + 64 * c) ^ SWZV(dd)));
                o_[dt] = __builtin_amdgcn_mfma_f32_16x16x32_bf16(pa, bv, o_[dt], 0, 0, 0);
            }
        }
        __builtin_amdgcn_s_setprio(0);
    };

    const int mymaxA = qA * 64 + w * 16 + 15;
    for (int kt = 0; kt < ntile; kt++) {
        bf16x8 kN[2], vN[2];
        const bool pre = (kt + 1 < ntile);
        if (pre) {
            #pragma unroll
            for (int p = 0; p < 2; p++) {
                const int row = srow + 32 * p;
                kN[p] = *(const bf16x8*)(K + base + (size_t)((kt + 1) * 64 + row) * ldq + scol);
                vN[p] = *(const bf16x8*)(V + base + (size_t)((kt + 1) * 64 + row) * ldq + scol);
            }
        }
        compute(qB, aqB, oB, mB, sB, kt);
        if (kt * 64 <= mymaxA) compute(qA, aqA, oA, mA, sA, kt);
        if (pre) {
            #pragma unroll
            for (int p = 0; p < 2; p++) {
                const int row = srow + 32 * p;
                *(bf16x8*)((char*)&ks[cur ^ 1][0] + ((row * 128 + scol * 2) ^ ((row & 7) << 4))) = kN[p];
                #pragma unroll
                for (int j2 = 0; j2 < 8; j2++) {
                    const int d = scol + j2;
                    *(unsigned short*)((char*)&vt[cur ^ 1][0] + ((d * 128 + row * 2) ^ SWZV(d))) =
                        (unsigned short)vN[p][j2];
                }
            }
        }
        __syncthreads();
        cur ^= 1;
    }

    #pragma unroll
    for (int j = 0; j < 4; j++) {
        const float invA = 1.f / sA[j];
        const float invB = 1.f / sB[j];
        const int rowA = qA * 64 + w * 16 + lg * 4 + j;
        const int rowB = qB * 64 + w * 16 + lg * 4 + j;
        unsigned short* opA = O + obase + (size_t)rowA * DM;
        unsigned short* opB = O + obase + (size_t)rowB * DM;
        #pragma unroll
        for (int dt = 0; dt < 4; dt++) {
            opA[dt * 16 + lq] = f2b(oA[dt][j] * invA);
            opB[dt * 16 + lq] = f2b(oB[dt][j] * invB);
        }
    }
}
#undef SWZV

// ---------------- fused knowledge: 32 tokens/block, shared K-stream, score + top-8 + gather ----------------
#define CE(a, b) { float hi_ = fmaxf(a, b), lo_ = fminf(a, b); a = hi_; b = lo_; }
__global__ void __launch_bounds__(512, 2) know_kernel(const unsigned short* __restrict__ Qmb,
                                                      const unsigned short* __restrict__ kKb,
                                                      const float* __restrict__ kV,
                                                      float* __restrict__ out) {
    const int t = threadIdx.x;
    const int w = t >> 6, l = t & 63, lq = l & 15, lg = l >> 4;
    const int tok0 = blockIdx.x * 32;
    __shared__ unsigned short ks[8][16 * 128];
    __shared__ float cs[32][64];

    bf16x8 aq[2][4];
    #pragma unroll
    for (int g = 0; g < 2; g++) {
        const unsigned short* qp = Qmb + (size_t)(tok0 + g * 16 + lq) * 128 + lg * 8;
        #pragma unroll
        for (int c = 0; c < 4; c++) aq[g][c] = *(const bf16x8*)(qp + c * 32);
    }

    float L[2][4][8];
    #pragma unroll
    for (int g = 0; g < 2; g++)
        #pragma unroll
        for (int j = 0; j < 4; j++)
            #pragma unroll
            for (int s = 0; s < 8; s++) L[g][j][s] = __uint_as_float(0xF2000000u | (unsigned)s);

    const unsigned short* gsrc = kKb + (((size_t)w * 2048) << 7) + l * 8;
    unsigned short* myks = &ks[w][0];

    bf16x8 vreg[4];
    #pragma unroll
    for (int p = 0; p < 4; p++) vreg[p] = *(const bf16x8*)(gsrc + p * 512);

    for (int t4 = 0; t4 < 32; t4++) {
        float B[2][4][4];
        #pragma unroll
        for (int sub = 0; sub < 4; sub++) {
            const int kt = t4 * 4 + sub;
            #pragma unroll
            for (int p = 0; p < 4; p++) {
                const int e = p * 512 + l * 8;
                const int row = e >> 7;
                *(bf16x8*)((char*)myks + ((e * 2) ^ ((row & 7) << 4))) = vreg[p];
            }
            if (kt < 127) {
                const unsigned short* src2 = gsrc + (size_t)(kt + 1) * 2048;
                #pragma unroll
                for (int p = 0; p < 4; p++) vreg[p] = *(const bf16x8*)(src2 + p * 512);
            }
            {
                const char* kb = (const char*)myks + lq * 256;
                const int sw = (lq & 7) << 4;
                f32x4 s0 = {0.f, 0.f, 0.f, 0.f};
                f32x4 s1 = {0.f, 0.f, 0.f, 0.f};
                #pragma unroll
                for (int c = 0; c < 4; c++) {
                    bf16x8 bv = *(const bf16x8*)(kb + ((c * 64 + lg * 16) ^ sw));
                    s0 = __builtin_amdgcn_mfma_f32_16x16x32_bf16(aq[0][c], bv, s0, 0, 0, 0);
                    s1 = __builtin_amdgcn_mfma_f32_16x16x32_bf16(aq[1][c], bv, s1, 0, 0, 0);
                }
                const unsigned keyb = (unsigned)(w * 2048 + kt * 16 + lq);
                #pragma unroll
                for (int j = 0; j < 4; j++) {
                    B[0][j][sub] = __uint_as_float((__float_as_uint(s0[j]) & 0xFFFFC000u) | keyb);
                    B[1][j][sub] = __uint_as_float((__float_as_uint(s1[j]) & 0xFFFFC000u) | keyb);
                }
            }
        }
        #pragma unroll
        for (int g = 0; g < 2; g++)
            #pragma unroll
            for (int j = 0; j < 4; j++) {
                const float bmax = fmaxf(fmaxf(B[g][j][0], B[g][j][1]), fmaxf(B[g][j][2], B[g][j][3]));
                if (__any(bmax > L[g][j][7])) {
                    CE(B[g][j][0], B[g][j][2]); CE(B[g][j][1], B[g][j][3]);
                    CE(B[g][j][0], B[g][j][1]); CE(B[g][j][2], B[g][j][3]);
                    CE(B[g][j][1], B[g][j][2]);
                    L[g][j][4] = fmaxf(L[g][j][4], B[g][j][3]);
                    L[g][j][5] = fmaxf(L[g][j][5], B[g][j][2]);
                    L[g][j][6] = fmaxf(L[g][j][6], B[g][j][1]);
                    L[g][j][7] = fmaxf(L[g][j][7], B[g][j][0]);
                    CE(L[g][j][0], L[g][j][4]); CE(L[g][j][1], L[g][j][5]); CE(L[g][j][2], L[g][j][6]); CE(L[g][j][3], L[g][j][7]);
                    CE(L[g][j][0], L[g][j][2]); CE(L[g][j][1], L[g][j][3]); CE(L[g][j][4], L[g][j][6]); CE(L[g][j][5], L[g][j][7]);
                    CE(L[g][j][0], L[g][j][1]); CE(L[g][j][2], L[g][j][3]); CE(L[g][j][4], L[g][j][5]); CE(L[g][j][6], L[g][j][7]);
                }
            }
    }
    // cross-lq butterfly merge: 16 lq lanes -> wave top-8 per (g, j)
    #pragma unroll
    for (int g = 0; g < 2; g++)
        #pragma unroll
        for (int j = 0; j < 4; j++) {
            #pragma unroll
            for (int d = 1; d < 16; d <<= 1) {
                float P[8];
                #pragma unroll
                for (int s = 0; s < 8; s++) P[s] = __shfl_xor(L[g][j][s], d);
                L[g][j][0] = fmaxf(L[g][j][0], P[7]);
                L[g][j][1] = fmaxf(L[g][j][1], P[6]);
                L[g][j][2] = fmaxf(L[g][j][2], P[5]);
                L[g][j][3] = fmaxf(L[g][j][3], P[4]);
                L[g][j][4] = fmaxf(L[g][j][4], P[3]);
                L[g][j][5] = fmaxf(L[g][j][5], P[2]);
                L[g][j][6] = fmaxf(L[g][j][6], P[1]);
                L[g][j][7] = fmaxf(L[g][j][7], P[0]);
                CE(L[g][j][0], L[g][j][4]); CE(L[g][j][1], L[g][j][5]); CE(L[g][j][2], L[g][j][6]); CE(L[g][j][3], L[g][j][7]);
                CE(L[g][j][0], L[g][j][2]); CE(L[g][j][1], L[g][j][3]); CE(L[g][j][4], L[g][j][6]); CE(L[g][j][5], L[g][j][7]);
                CE(L[g][j][0], L[g][j][1]); CE(L[g][j][2], L[g][j][3]); CE(L[g][j][4], L[g][j][5]); CE(L[g][j][6], L[g][j][7]);
            }
        }
    if (lq == 0) {
        #pragma unroll
        for (int g = 0; g < 2; g++)
            #pragma unroll
            for (int j = 0; j < 4; j++) {
                const int tl = g * 16 + lg * 4 + j;
                #pragma unroll
                for (int ss = 0; ss < 8; ss++) cs[tl][w * 8 + ss] = L[g][j][ss];
            }
    }
    __syncthreads();

    // block merge + softmax + V gather: wave w handles local tokens 4w..4w+3
    #pragma unroll
    for (int ti = 0; ti < 4; ti++) {
        const int tl = w * 4 + ti;
        float lv = cs[tl][l];
        float topv[8]; int topi[8];
        #pragma unroll
        for (int kk = 0; kk < 8; kk++) {
            float m = lv;
            #pragma unroll
            for (int d = 1; d < 64; d <<= 1) m = fmaxf(m, __shfl_xor(m, d));
            topv[kk] = m;
            topi[kk] = (int)(__float_as_uint(m) & 0x3FFFu);
            lv = (lv == m) ? -1e31f : lv;
        }
        const float mx = topv[0];
        float e[8]; float ssum = 0.f;
        #pragma unroll
        for (int kk = 0; kk < 8; kk++) { e[kk] = __expf(topv[kk] - mx); ssum += e[kk]; }
        const float inv = 1.f / ssum;

        float4 acc[4];
        #pragma unroll
        for (int ch = 0; ch < 4; ch++) acc[ch] = float4{0.f, 0.f, 0.f, 0.f};
        #pragma unroll
        for (int kk = 0; kk < 8; kk++) {
            const float wk = e[kk] * inv;
            const float* vp = kV + ((size_t)topi[kk] << 10);
            #pragma unroll
            for (int ch = 0; ch < 4; ch++) {
                float4 v = *(const float4*)(vp + ch * 256 + l * 4);
                acc[ch].x += wk * v.x; acc[ch].y += wk * v.y;
                acc[ch].z += wk * v.z; acc[ch].w += wk * v.w;
            }
        }
        float* op = out + ((size_t)(tok0 + tl) << 10);
        #pragma unroll
        for (int ch = 0; ch < 4; ch++) {
            float4 o = *(const float4*)(op + ch * 256 + l * 4);
            o.x += acc[ch].x; o.y += acc[ch].y; o.z += acc[ch].z; o.w += acc[ch].w;
            *(float4*)(op + ch * 256 + l * 4) = o;
        }
    }
}
#undef CE

extern "C" void kernel_launch(void* const* d_in, const int* in_sizes, int n_in,
                              void* d_out, int out_size, void* d_ws, size_t ws_size,
                              hipStream_t stream) {
    const float* x    = (const float*)d_in[0];
    const float* imp  = (const float*)d_in[1];
    const float* Wc   = (const float*)d_in[2];
    const float* WQr  = (const float*)d_in[3];
    const float* WKr  = (const float*)d_in[4];
    const float* WVr  = (const float*)d_in[5];
    const float* Wm   = (const float*)d_in[6];
    const float* cneu = (const float*)d_in[7];
    const float* epool= (const float*)d_in[8];
    const float* kK   = (const float*)d_in[9];
    const float* kV   = (const float*)d_in[10];
    const float* WO   = (const float*)d_in[11];
    const float* ln1s = (const float*)d_in[12];
    const float* ln1b = (const float*)d_in[13];
    const float* ln2s = (const float*)d_in[14];
    const float* ln2b = (const float*)d_in[15];
    float* out = (float*)d_out;

    float* ws = (float*)d_ws;
    size_t o = 0;
    unsigned short* n1h = (unsigned short*)(ws + o); o += (size_t)BD * SD * DM / 2;
    unsigned short* n1l = (unsigned short*)(ws + o); o += (size_t)BD * SD * DM / 2;
    float* lgt   = ws + o; o += (size_t)BD * SD * 192;
    float* partial = ws + o; o += (size_t)BD * 16 * 224;
    int*   ridx  = (int*)(ws + o); o += (size_t)BD * 5 * 8;
    float* rw    = ws + o; o += (size_t)BD * 5 * 8;
    unsigned short* WTh = (unsigned short*)(ws + o); o += (size_t)256 * 1024 / 2;
    unsigned short* WTl = (unsigned short*)(ws + o); o += (size_t)256 * 1024 / 2;
    unsigned short* scompT = (unsigned short*)(ws + o); o += (size_t)BD * RK * DM / 2;
    unsigned short* E3t = (unsigned short*)(ws + o); o += (size_t)BD * 3 * DM * RK / 2;
    unsigned short* hb  = (unsigned short*)(ws + o); o += (size_t)BD * SD * RK / 2;
    unsigned short* QKV16 = (unsigned short*)(ws + o); o += (size_t)BD * SD * 3072 / 2;
    unsigned short* attnb = (unsigned short*)(ws + o); o += (size_t)BD * SD * DM / 2;
    unsigned short* WOt = (unsigned short*)(ws + o); o += (size_t)DM * DM / 2;
    unsigned short* kKb = (unsigned short*)(ws + o); o += (size_t)NK * RK / 2;
    unsigned short* Qmb = (unsigned short*)(ws + o); o += (size_t)BD * SD * RK / 2;

    const int NTOK = BD * SD;
    const long long sE3 = (long long)3 * DM * RK;

    // fused prep (concatw | tcvt WO | cvt kK)
    prep_kernel<<<3328, 256, 0, stream>>>(Wc, WQr, WKr, WVr, Wm, WTh, WTl, WO, WOt, kK, kKb);

    // phase 1
    ln_kernel<<<NTOK, 256, 0, stream>>>(x, ln1s, ln1b, n1h, n1l);
    gemm_split<<<dim3(3, NTOK / 64), 256, 0, stream>>>(n1h, n1l, WTh, WTl, lgt, 192, DM);
    softpref_red<<<dim3(BD, 16), 256, 0, stream>>>(lgt, imp, partial);
    topk_kernel<<<1, 64, 0, stream>>>(partial, ridx, rw, 0, 4);
    combine_all_kernel<<<1024, 256, 0, stream>>>(cneu, epool, ridx, rw, scompT, E3t);
    gemm_h<<<dim3(1, SD / 64, BD), 256, 0, stream>>>(n1h, scompT, hb,
        DM, (long long)SD * DM, (long long)RK * DM, (long long)SD * RK);
    gemm_bf16<1, 0><<<dim3(24, 8, BD), 256, 0, stream>>>(hb, E3t, nullptr, QKV16,
        SD, 3072, RK, (long long)SD * RK, sE3, (long long)SD * 3072);
    attn_mfma_kernel<<<dim3(8, NH, BD), 256, 0, stream>>>(QKV16, QKV16 + 1024, QKV16 + 2048,
        attnb, 3072);
    gemm_bf16<0, 1><<<dim3(8, 64, 1), 256, 0, stream>>>(attnb, WOt, x, out,
        NTOK, DM, DM, 0, 0, 0);

    // phase 2
    ln_kernel<<<NTOK, 256, 0, stream>>>(out, ln2s, ln2b, n1h, n1l);
    gemm_split_sm2<<<NTOK / 64, 256, 0, stream>>>(n1h, n1l,
        WTh + (size_t)192 * 1024, WTl + (size_t)192 * 1024, imp, partial);
    topk_kernel<<<1, 64, 0, stream>>>(partial, ridx, rw, 4, 1);
    combine_t_kernel<<<dim3(2, 16, BD), 256, 0, stream>>>(cneu, ridx, rw, 4, 8, scompT, DM, RK,
        (long long)DM * RK);
    gemm_h<<<dim3(1, SD / 64, BD), 256, 0, stream>>>(n1h, scompT, Qmb,
        DM, (long long)SD * DM, (long long)RK * DM, (long long)SD * RK);
    know_kernel<<<NTOK / 32, 512, 0, stream>>>(Qmb, kKb, kV, out);
}